// Round 2
// baseline (1603.265 us; speedup 1.0000x reference)
//
#include <hip/hip_runtime.h>
#include <cstdint>
#include <cstddef>

// GatedDeltaNet forward, MI355X/gfx950.
// Inputs/outputs are fp32 (reference computes in jnp.float32).
// Pipeline: cast(x,Wqkv,Wz,Wout -> bf16) -> [gemm qkv] [gemm z] [proj b/a]
//           -> conv1d+silu (fp32) -> l2norm q,k -> gated delta-rule recurrence
//           -> gated RMSNorm*silu(z) (bf16 out) -> [gemm out -> fp32 d_out].

typedef unsigned short ushort_t;
typedef __attribute__((ext_vector_type(8))) __bf16 bf16x8;
typedef __attribute__((ext_vector_type(4))) float f32x4;
typedef __attribute__((ext_vector_type(4))) short short4v;

#define B_   2
#define T_   2048
#define HID_ 2048
#define NK_  8
#define NV_  16
#define HD_  128
#define KD_  1024
#define VD_  2048
#define CD_  4096

__device__ __forceinline__ float b2f(ushort_t u) {
  union { unsigned int i; float f; } v; v.i = ((unsigned int)u) << 16; return v.f;
}
__device__ __forceinline__ ushort_t f2b(float f) {   // RNE bf16 round
  unsigned int x = __builtin_bit_cast(unsigned int, f);
  unsigned int r = x + 0x7fffu + ((x >> 16) & 1u);
  return (ushort_t)(r >> 16);
}

// ---------------------------------------------------------------------------
// fp32 -> bf16 cast (vectorized: 4 elems/thread)
// ---------------------------------------------------------------------------
__global__ __launch_bounds__(256)
void k_cast_bf16(const float* __restrict__ in, ushort_t* __restrict__ out, int n4) {
  const int i = blockIdx.x * 256 + threadIdx.x;
  if (i >= n4) return;
  float4 v = *(const float4*)(in + (size_t)i * 4);
  short4v o;
  o[0] = (short)f2b(v.x); o[1] = (short)f2b(v.y);
  o[2] = (short)f2b(v.z); o[3] = (short)f2b(v.w);
  *(short4v*)(out + (size_t)i * 4) = o;
}

// ---------------------------------------------------------------------------
// GEMM: C[m,n] = sum_k A[m,k] * B[n,k]   (A: MxK row-major bf16, B: NxK bf16)
// m97 structure: 128x128 tile, BK=32, 4 waves, global_load_lds width 16.
// ---------------------------------------------------------------------------
template <typename OutT>
__global__ __launch_bounds__(256)
void k_gemm_bt(const ushort_t* __restrict__ A, const ushort_t* __restrict__ Bw,
               OutT* __restrict__ C, int M, int N, int K) {
  __shared__ alignas(16) ushort_t As[128 * 32];
  __shared__ alignas(16) ushort_t Bs[128 * 32];
  const int tid  = threadIdx.x;
  const int lane = tid & 63;
  const int wave = tid >> 6;
  const int wr = wave >> 1, wc = wave & 1;
  const size_t row0 = (size_t)blockIdx.y * 128;
  const size_t col0 = (size_t)blockIdx.x * 128;

  f32x4 acc[4][4] = {};
  const int fr = lane & 15;            // fragment row/col
  const int ks = (lane >> 4) * 8;      // k-slice within BK=32

  for (int kt = 0; kt < K; kt += 32) {
    __syncthreads();                   // LDS reads of prev tile done
#pragma unroll
    for (int ch = 0; ch < 2; ++ch) {
      const int li  = ch * 256 + tid;  // 16B-unit index, 512 per 8KB tile
      const int row = li >> 2;
      const int cp  = li & 3;
      const ushort_t* ga = A  + (row0 + row) * (size_t)K + kt + cp * 8;
      const ushort_t* gb = Bw + (col0 + row) * (size_t)K + kt + cp * 8;
      ushort_t* la = As + ((li >> 6) << 9);  // wave-uniform 1KB chunk base
      ushort_t* lb = Bs + ((li >> 6) << 9);
      __builtin_amdgcn_global_load_lds(
          (const __attribute__((address_space(1))) unsigned int*)ga,
          (__attribute__((address_space(3))) unsigned int*)la, 16, 0, 0);
      __builtin_amdgcn_global_load_lds(
          (const __attribute__((address_space(1))) unsigned int*)gb,
          (__attribute__((address_space(3))) unsigned int*)lb, 16, 0, 0);
    }
    __syncthreads();                   // vmcnt(0) drained by compiler

    bf16x8 af[4], bfv[4];
#pragma unroll
    for (int m = 0; m < 4; ++m)
      af[m]  = *(const bf16x8*)&As[(wr * 64 + m * 16 + fr) * 32 + ks];
#pragma unroll
    for (int n = 0; n < 4; ++n)
      bfv[n] = *(const bf16x8*)&Bs[(wc * 64 + n * 16 + fr) * 32 + ks];
#pragma unroll
    for (int m = 0; m < 4; ++m)
#pragma unroll
      for (int n = 0; n < 4; ++n)
        acc[m][n] = __builtin_amdgcn_mfma_f32_16x16x32_bf16(af[m], bfv[n], acc[m][n], 0, 0, 0);
  }

  const int r4 = (lane >> 4) * 4;      // C/D: col=lane&15, row=(lane>>4)*4+reg
#pragma unroll
  for (int m = 0; m < 4; ++m)
#pragma unroll
    for (int n = 0; n < 4; ++n)
#pragma unroll
      for (int j = 0; j < 4; ++j) {
        const size_t row = row0 + wr * 64 + m * 16 + r4 + j;
        const size_t col = col0 + wc * 64 + n * 16 + fr;
        if constexpr (sizeof(OutT) == 4)
          C[row * (size_t)N + col] = acc[m][n][j];
        else
          C[row * (size_t)N + col] = (OutT)f2b(acc[m][n][j]);
      }
}

// ---------------------------------------------------------------------------
// b/a projection + activation (fp32 in): beta = sigmoid(x@Wb^T),
// decay = exp(-exp(A_log) * softplus(x@Wa^T + dt_bias)). One block per (b,t).
// ---------------------------------------------------------------------------
__global__ __launch_bounds__(256)
void k_proj_ba(const float* __restrict__ x, const float* __restrict__ Wb,
               const float* __restrict__ Wa, const float* __restrict__ dtb,
               const float* __restrict__ alog,
               float* __restrict__ beta, float* __restrict__ decay) {
  __shared__ float xs[HID_];
  __shared__ float part[32][8];
  const int bt = blockIdx.x, tid = threadIdx.x;
  const float* xr = x + (size_t)bt * HID_;
  *(float4*)&xs[tid * 8]     = *(const float4*)&xr[tid * 8];
  *(float4*)&xs[tid * 8 + 4] = *(const float4*)&xr[tid * 8 + 4];
  __syncthreads();
  const int o = tid >> 3, seg = tid & 7;
  const float* W = (o < 16) ? (Wb + (size_t)o * HID_) : (Wa + (size_t)(o - 16) * HID_);
  float s = 0.f;
  for (int k = seg * 256; k < seg * 256 + 256; k += 4) {
    float4 wv = *(const float4*)&W[k];
    float4 xv = *(const float4*)&xs[k];
    s += wv.x * xv.x + wv.y * xv.y + wv.z * xv.z + wv.w * xv.w;
  }
  part[o][seg] = s;
  __syncthreads();
  if (tid < 32) {
    float tsum = 0.f;
#pragma unroll
    for (int i = 0; i < 8; ++i) tsum += part[tid][i];
    if (tid < 16) {
      beta[(size_t)bt * NV_ + tid] = 1.f / (1.f + expf(-tsum));
    } else {
      const int h = tid - 16;
      float aa = tsum + dtb[h];
      float sp = (aa > 20.f) ? aa : log1pf(expf(aa));
      decay[(size_t)bt * NV_ + h] = expf(-expf(alog[h]) * sp);
    }
  }
}

// ---------------------------------------------------------------------------
// Depthwise causal conv1d (K=4, left zero-pad) + silu, bf16 in -> fp32 out.
// Thread handles 4 consecutive channels at one (b,t). conv_w is fp32.
// ---------------------------------------------------------------------------
__global__ __launch_bounds__(256)
void k_conv_silu(const ushort_t* __restrict__ qkv, const float* __restrict__ cw,
                 float* __restrict__ act) {
  const unsigned idx = blockIdx.x * 256u + threadIdx.x;  // B*T*CD/4 total
  const unsigned c4  = idx & (CD_ / 4 - 1);
  const unsigned bt  = idx >> 10;                        // / (CD_/4)
  const int t = bt & (T_ - 1);
  const int c = c4 * 4;
  const ushort_t* rowp = qkv + (size_t)bt * CD_ + c;
  float wf[4][4];
#pragma unroll
  for (int i = 0; i < 4; ++i) {
    float4 w = *(const float4*)&cw[(c + i) * 4];
    wf[i][0] = w.x; wf[i][1] = w.y; wf[i][2] = w.z; wf[i][3] = w.w;
  }
  float a[4] = {0.f, 0.f, 0.f, 0.f};
#pragma unroll
  for (int j = 0; j < 4; ++j) {
    const int tt = t - 3 + j;
    if (tt >= 0) {
      short4v iv = *(const short4v*)(rowp + ((ptrdiff_t)j - 3) * CD_);
#pragma unroll
      for (int i = 0; i < 4; ++i) a[i] += b2f((ushort_t)iv[i]) * wf[i][j];
    }
  }
  float4 o;
  o.x = a[0] / (1.f + expf(-a[0]));
  o.y = a[1] / (1.f + expf(-a[1]));
  o.z = a[2] / (1.f + expf(-a[2]));
  o.w = a[3] / (1.f + expf(-a[3]));
  *(float4*)(act + (size_t)bt * CD_ + c) = o;
}

// ---------------------------------------------------------------------------
// L2-normalize q (with HD^-1/2 scale) and k rows in-place (fp32). Wave per row.
// ---------------------------------------------------------------------------
__global__ __launch_bounds__(256)
void k_l2norm_qk(float* __restrict__ act) {
  const int row  = blockIdx.x * 4 + (threadIdx.x >> 6);  // B*T*16 rows
  const int lane = threadIdx.x & 63;
  const int bt = row >> 4, s = row & 15;
  float* p = act + (size_t)bt * CD_ + (s < 8 ? s * HD_ : KD_ + (s - 8) * HD_);
  float2 v = *(float2*)&p[lane * 2];
  float ss = v.x * v.x + v.y * v.y;
#pragma unroll
  for (int m = 1; m < 64; m <<= 1) ss += __shfl_xor(ss, m);
  float scale = 1.f / fmaxf(sqrtf(ss), 1e-12f);
  if (s < 8) scale *= 0.08838834764831845f;  // HD^-0.5
  v.x *= scale; v.y *= scale;
  *(float2*)&p[lane * 2] = v;
}

// ---------------------------------------------------------------------------
// Gated delta-rule recurrence. State columns are independent:
//   s_j <- d*s_j + beta*(v_j - d*(k.s_j))*k ,  o_j = q.s_j (post-update).
// Block = 1 wave = (b, head, 8 columns); 8 lanes/col, 16 state rows/lane.
// Register-double-buffered loads hide L2 latency across the sequential chain.
// ---------------------------------------------------------------------------
__global__ __launch_bounds__(64)
void k_recur(const float* __restrict__ act, const float* __restrict__ beta,
             const float* __restrict__ decay, float* __restrict__ ob) {
  const int gid = blockIdx.x;            // B*NV*16
  const int grp = gid & 15;
  const int h   = (gid >> 4) & 15;
  const int b   = gid >> 8;
  const int l   = threadIdx.x;
  const int cl = l >> 3, ro = l & 7;
  const int col = grp * 8 + cl;
  const int hq  = h >> 1;                // GQA: v-head h uses q/k head h/2
  const float* baseQ = act + (size_t)b * T_ * CD_ + hq * HD_ + ro * 16;
  const float* baseK = baseQ + KD_;
  const float* baseV = act + (size_t)b * T_ * CD_ + 2 * KD_ + h * HD_ + col;
  const float* bp = beta  + (size_t)b * T_ * NV_ + h;
  const float* dp = decay + (size_t)b * T_ * NV_ + h;
  float* op = ob + ((size_t)b * T_ * NV_ + h) * HD_ + col;

  float s[16];
#pragma unroll
  for (int j = 0; j < 16; ++j) s[j] = 0.f;

  auto ld = [&](float4* k4, float4* q4, float& vc, float& bb, float& dd, int t) {
    const float* rk = baseK + (size_t)t * CD_;
    const float* rq = baseQ + (size_t)t * CD_;
#pragma unroll
    for (int i = 0; i < 4; ++i) {
      k4[i] = *(const float4*)(rk + i * 4);
      q4[i] = *(const float4*)(rq + i * 4);
    }
    vc = baseV[(size_t)t * CD_];
    bb = bp[(size_t)t * NV_];
    dd = dp[(size_t)t * NV_];
  };

  auto step = [&](const float4* k4, const float4* q4, float vc, float bb, float dd, int t) {
    float kr[16], qr[16];
#pragma unroll
    for (int i = 0; i < 4; ++i) {
      kr[4*i] = k4[i].x; kr[4*i+1] = k4[i].y; kr[4*i+2] = k4[i].z; kr[4*i+3] = k4[i].w;
      qr[4*i] = q4[i].x; qr[4*i+1] = q4[i].y; qr[4*i+2] = q4[i].z; qr[4*i+3] = q4[i].w;
    }
    float kts = 0.f;
#pragma unroll
    for (int j = 0; j < 16; ++j) kts += kr[j] * s[j];
    kts += __shfl_xor(kts, 1); kts += __shfl_xor(kts, 2); kts += __shfl_xor(kts, 4);
    const float w = bb * (vc - dd * kts);
#pragma unroll
    for (int j = 0; j < 16; ++j) s[j] = dd * s[j] + kr[j] * w;
    float ov = 0.f;
#pragma unroll
    for (int j = 0; j < 16; ++j) ov += qr[j] * s[j];
    ov += __shfl_xor(ov, 1); ov += __shfl_xor(ov, 2); ov += __shfl_xor(ov, 4);
    if (ro == 0) op[(size_t)t * (NV_ * HD_)] = ov;
  };

  float4 ka[4], qa[4], kb[4], qb[4];
  float va, ba2, da, vb, bb2, db;
  ld(ka, qa, va, ba2, da, 0);
  for (int t = 0; t < T_; t += 2) {
    ld(kb, qb, vb, bb2, db, t + 1);
    step(ka, qa, va, ba2, da, t);
    if (t + 2 < T_) ld(ka, qa, va, ba2, da, t + 2);
    step(kb, qb, vb, bb2, db, t + 1);
  }
}

// ---------------------------------------------------------------------------
// Gated RMSNorm: out = (o/rms(o)) * norm_w * silu(z); fp32 o, bf16 z,
// fp32 norm_w -> bf16 out (final GEMM operand).
// ---------------------------------------------------------------------------
__global__ __launch_bounds__(256)
void k_gate_rms(const float* __restrict__ ob, const ushort_t* __restrict__ z,
                const float* __restrict__ nw, ushort_t* __restrict__ og) {
  const int row  = blockIdx.x * 4 + (threadIdx.x >> 6);  // B*T*NV rows
  const int lane = threadIdx.x & 63;
  const float* op = ob + (size_t)row * HD_;
  float2 v = *(const float2*)&op[lane * 2];
  float ss = v.x * v.x + v.y * v.y;
#pragma unroll
  for (int m = 1; m < 64; m <<= 1) ss += __shfl_xor(ss, m);
  const float r = 1.f / sqrtf(ss * (1.f / HD_) + 1e-6f);
  unsigned int zz = *(const unsigned int*)&z[(size_t)row * HD_ + lane * 2];
  float z0 = b2f((ushort_t)(zz & 0xffffu));
  float z1 = b2f((ushort_t)(zz >> 16));
  float2 w = *(const float2*)&nw[lane * 2];
  float g0 = z0 / (1.f + expf(-z0));
  float g1 = z1 / (1.f + expf(-z1));
  unsigned int pack = (unsigned int)f2b(v.x * r * w.x * g0)
                    | ((unsigned int)f2b(v.y * r * w.y * g1) << 16);
  *(unsigned int*)&og[(size_t)row * HD_ + lane * 2] = pack;
}

// ---------------------------------------------------------------------------
extern "C" void kernel_launch(void* const* d_in, const int* in_sizes, int n_in,
                              void* d_out, int out_size, void* d_ws, size_t ws_size,
                              hipStream_t stream) {
  const float* x    = (const float*)d_in[0];
  const float* Wqkv = (const float*)d_in[1];
  const float* Wz   = (const float*)d_in[2];
  const float* Wb   = (const float*)d_in[3];
  const float* Wa   = (const float*)d_in[4];
  const float* cw   = (const float*)d_in[5];
  const float* dtb  = (const float*)d_in[6];
  const float* alog = (const float*)d_in[7];
  const float* nw   = (const float*)d_in[8];
  const float* Wout = (const float*)d_in[9];

  char* p = (char*)d_ws;
  ushort_t* qkv_raw = (ushort_t*)p; p += (size_t)B_ * T_ * CD_ * 2;       // 33.5 MB
  ushort_t* zbuf    = (ushort_t*)p; p += (size_t)B_ * T_ * VD_ * 2;       // 16.8 MB
  char*     actBase = p;
  float*    act     = (float*)p;    p += (size_t)B_ * T_ * CD_ * 4;       // 67.1 MB
  float*    betaB   = (float*)p;    p += (size_t)B_ * T_ * NV_ * 4;
  float*    decayB  = (float*)p;    p += (size_t)B_ * T_ * NV_ * 4;
  float*    obuf    = (float*)p;    p += (size_t)B_ * T_ * NV_ * HD_ * 4; // 33.5 MB
  ushort_t* WoutB   = (ushort_t*)p; p += (size_t)HID_ * VD_ * 2;          // 8.4 MB
  // bf16 cast buffers aliased into act region (dead before conv writes act):
  ushort_t* xB    = (ushort_t*)(actBase);                                 // 16.8 MB
  ushort_t* WqkvB = (ushort_t*)(actBase + (size_t)B_ * T_ * HID_ * 2);    // 16.8 MB
  ushort_t* WzB   = (ushort_t*)(actBase + (size_t)B_ * T_ * HID_ * 2
                                        + (size_t)CD_ * HID_ * 2);        // 8.4 MB
  ushort_t* outg  = qkv_raw;        // reuse: qkv_raw dead after conv

  const int M = B_ * T_;  // 4096

  hipLaunchKernelGGL(k_cast_bf16, dim3(M * HID_ / 4 / 256), dim3(256), 0, stream,
                     x, xB, M * HID_ / 4);
  hipLaunchKernelGGL(k_cast_bf16, dim3(CD_ * HID_ / 4 / 256), dim3(256), 0, stream,
                     Wqkv, WqkvB, CD_ * HID_ / 4);
  hipLaunchKernelGGL(k_cast_bf16, dim3(VD_ * HID_ / 4 / 256), dim3(256), 0, stream,
                     Wz, WzB, VD_ * HID_ / 4);
  hipLaunchKernelGGL(k_cast_bf16, dim3(HID_ * VD_ / 4 / 256), dim3(256), 0, stream,
                     Wout, WoutB, HID_ * VD_ / 4);

  hipLaunchKernelGGL(k_gemm_bt<ushort_t>, dim3(CD_ / 128, M / 128), dim3(256), 0, stream,
                     xB, WqkvB, qkv_raw, M, CD_, HID_);
  hipLaunchKernelGGL(k_gemm_bt<ushort_t>, dim3(VD_ / 128, M / 128), dim3(256), 0, stream,
                     xB, WzB, zbuf, M, VD_, HID_);
  hipLaunchKernelGGL(k_proj_ba, dim3(M), dim3(256), 0, stream,
                     x, Wb, Wa, dtb, alog, betaB, decayB);
  hipLaunchKernelGGL(k_conv_silu, dim3(M * CD_ / 4 / 256), dim3(256), 0, stream,
                     qkv_raw, cw, act);
  hipLaunchKernelGGL(k_l2norm_qk, dim3(M * 16 / 4), dim3(256), 0, stream, act);
  hipLaunchKernelGGL(k_recur, dim3(B_ * NV_ * 16), dim3(64), 0, stream,
                     act, betaB, decayB, obuf);
  hipLaunchKernelGGL(k_gate_rms, dim3(M * NV_ / 4), dim3(256), 0, stream,
                     obuf, zbuf, nw, outg);
  hipLaunchKernelGGL(k_gemm_bt<float>, dim3(HID_ / 128, M / 128), dim3(256), 0, stream,
                     outg, WoutB, (float*)d_out, M, HID_, VD_);
}

// Round 3
// 1498.095 us; speedup vs baseline: 1.0702x; 1.0702x over previous
//
#include <hip/hip_runtime.h>
#include <cstdint>
#include <cstddef>

// GatedDeltaNet forward, MI355X/gfx950.
// Inputs/outputs are fp32 (reference computes in jnp.float32).
// Pipeline: cast(x,Wqkv,Wz,Wout -> bf16) -> [gemm qkv] [gemm z] [proj b/a]
//           -> conv1d+silu (fp32) -> l2norm q,k -> gated delta-rule recurrence
//           -> gated RMSNorm*silu(z) (bf16 out) -> [gemm out -> fp32 d_out].
// R2: k_recur rewritten with 8-deep register prefetch + tree reductions
//     (was latency-bound at 1270 cy/step on L3 loads with 1-step prefetch).

typedef unsigned short ushort_t;
typedef __attribute__((ext_vector_type(8))) __bf16 bf16x8;
typedef __attribute__((ext_vector_type(4))) float f32x4;
typedef __attribute__((ext_vector_type(4))) short short4v;

#define B_   2
#define T_   2048
#define HID_ 2048
#define NK_  8
#define NV_  16
#define HD_  128
#define KD_  1024
#define VD_  2048
#define CD_  4096

__device__ __forceinline__ float b2f(ushort_t u) {
  union { unsigned int i; float f; } v; v.i = ((unsigned int)u) << 16; return v.f;
}
__device__ __forceinline__ ushort_t f2b(float f) {   // RNE bf16 round
  unsigned int x = __builtin_bit_cast(unsigned int, f);
  unsigned int r = x + 0x7fffu + ((x >> 16) & 1u);
  return (ushort_t)(r >> 16);
}

// ---------------------------------------------------------------------------
// fp32 -> bf16 cast (vectorized: 4 elems/thread)
// ---------------------------------------------------------------------------
__global__ __launch_bounds__(256)
void k_cast_bf16(const float* __restrict__ in, ushort_t* __restrict__ out, int n4) {
  const int i = blockIdx.x * 256 + threadIdx.x;
  if (i >= n4) return;
  float4 v = *(const float4*)(in + (size_t)i * 4);
  short4v o;
  o[0] = (short)f2b(v.x); o[1] = (short)f2b(v.y);
  o[2] = (short)f2b(v.z); o[3] = (short)f2b(v.w);
  *(short4v*)(out + (size_t)i * 4) = o;
}

// ---------------------------------------------------------------------------
// GEMM: C[m,n] = sum_k A[m,k] * B[n,k]   (A: MxK row-major bf16, B: NxK bf16)
// m97 structure: 128x128 tile, BK=32, 4 waves, global_load_lds width 16.
// ---------------------------------------------------------------------------
template <typename OutT>
__global__ __launch_bounds__(256)
void k_gemm_bt(const ushort_t* __restrict__ A, const ushort_t* __restrict__ Bw,
               OutT* __restrict__ C, int M, int N, int K) {
  __shared__ alignas(16) ushort_t As[128 * 32];
  __shared__ alignas(16) ushort_t Bs[128 * 32];
  const int tid  = threadIdx.x;
  const int lane = tid & 63;
  const int wave = tid >> 6;
  const int wr = wave >> 1, wc = wave & 1;
  const size_t row0 = (size_t)blockIdx.y * 128;
  const size_t col0 = (size_t)blockIdx.x * 128;

  f32x4 acc[4][4] = {};
  const int fr = lane & 15;            // fragment row/col
  const int ks = (lane >> 4) * 8;      // k-slice within BK=32

  for (int kt = 0; kt < K; kt += 32) {
    __syncthreads();                   // LDS reads of prev tile done
#pragma unroll
    for (int ch = 0; ch < 2; ++ch) {
      const int li  = ch * 256 + tid;  // 16B-unit index, 512 per 8KB tile
      const int row = li >> 2;
      const int cp  = li & 3;
      const ushort_t* ga = A  + (row0 + row) * (size_t)K + kt + cp * 8;
      const ushort_t* gb = Bw + (col0 + row) * (size_t)K + kt + cp * 8;
      ushort_t* la = As + ((li >> 6) << 9);  // wave-uniform 1KB chunk base
      ushort_t* lb = Bs + ((li >> 6) << 9);
      __builtin_amdgcn_global_load_lds(
          (const __attribute__((address_space(1))) unsigned int*)ga,
          (__attribute__((address_space(3))) unsigned int*)la, 16, 0, 0);
      __builtin_amdgcn_global_load_lds(
          (const __attribute__((address_space(1))) unsigned int*)gb,
          (__attribute__((address_space(3))) unsigned int*)lb, 16, 0, 0);
    }
    __syncthreads();                   // vmcnt(0) drained by compiler

    bf16x8 af[4], bfv[4];
#pragma unroll
    for (int m = 0; m < 4; ++m)
      af[m]  = *(const bf16x8*)&As[(wr * 64 + m * 16 + fr) * 32 + ks];
#pragma unroll
    for (int n = 0; n < 4; ++n)
      bfv[n] = *(const bf16x8*)&Bs[(wc * 64 + n * 16 + fr) * 32 + ks];
#pragma unroll
    for (int m = 0; m < 4; ++m)
#pragma unroll
      for (int n = 0; n < 4; ++n)
        acc[m][n] = __builtin_amdgcn_mfma_f32_16x16x32_bf16(af[m], bfv[n], acc[m][n], 0, 0, 0);
  }

  const int r4 = (lane >> 4) * 4;      // C/D: col=lane&15, row=(lane>>4)*4+reg
#pragma unroll
  for (int m = 0; m < 4; ++m)
#pragma unroll
    for (int n = 0; n < 4; ++n)
#pragma unroll
      for (int j = 0; j < 4; ++j) {
        const size_t row = row0 + wr * 64 + m * 16 + r4 + j;
        const size_t col = col0 + wc * 64 + n * 16 + fr;
        if constexpr (sizeof(OutT) == 4)
          C[row * (size_t)N + col] = acc[m][n][j];
        else
          C[row * (size_t)N + col] = (OutT)f2b(acc[m][n][j]);
      }
}

// ---------------------------------------------------------------------------
// b/a projection + activation (fp32 in): beta = sigmoid(x@Wb^T),
// decay = exp(-exp(A_log) * softplus(x@Wa^T + dt_bias)). One block per (b,t).
// ---------------------------------------------------------------------------
__global__ __launch_bounds__(256)
void k_proj_ba(const float* __restrict__ x, const float* __restrict__ Wb,
               const float* __restrict__ Wa, const float* __restrict__ dtb,
               const float* __restrict__ alog,
               float* __restrict__ beta, float* __restrict__ decay) {
  __shared__ float xs[HID_];
  __shared__ float part[32][8];
  const int bt = blockIdx.x, tid = threadIdx.x;
  const float* xr = x + (size_t)bt * HID_;
  *(float4*)&xs[tid * 8]     = *(const float4*)&xr[tid * 8];
  *(float4*)&xs[tid * 8 + 4] = *(const float4*)&xr[tid * 8 + 4];
  __syncthreads();
  const int o = tid >> 3, seg = tid & 7;
  const float* W = (o < 16) ? (Wb + (size_t)o * HID_) : (Wa + (size_t)(o - 16) * HID_);
  float s = 0.f;
  for (int k = seg * 256; k < seg * 256 + 256; k += 4) {
    float4 wv = *(const float4*)&W[k];
    float4 xv = *(const float4*)&xs[k];
    s += wv.x * xv.x + wv.y * xv.y + wv.z * xv.z + wv.w * xv.w;
  }
  part[o][seg] = s;
  __syncthreads();
  if (tid < 32) {
    float tsum = 0.f;
#pragma unroll
    for (int i = 0; i < 8; ++i) tsum += part[tid][i];
    if (tid < 16) {
      beta[(size_t)bt * NV_ + tid] = 1.f / (1.f + expf(-tsum));
    } else {
      const int h = tid - 16;
      float aa = tsum + dtb[h];
      float sp = (aa > 20.f) ? aa : log1pf(expf(aa));
      decay[(size_t)bt * NV_ + h] = expf(-expf(alog[h]) * sp);
    }
  }
}

// ---------------------------------------------------------------------------
// Depthwise causal conv1d (K=4, left zero-pad) + silu, bf16 in -> fp32 out.
// ---------------------------------------------------------------------------
__global__ __launch_bounds__(256)
void k_conv_silu(const ushort_t* __restrict__ qkv, const float* __restrict__ cw,
                 float* __restrict__ act) {
  const unsigned idx = blockIdx.x * 256u + threadIdx.x;  // B*T*CD/4 total
  const unsigned c4  = idx & (CD_ / 4 - 1);
  const unsigned bt  = idx >> 10;                        // / (CD_/4)
  const int t = bt & (T_ - 1);
  const int c = c4 * 4;
  const ushort_t* rowp = qkv + (size_t)bt * CD_ + c;
  float wf[4][4];
#pragma unroll
  for (int i = 0; i < 4; ++i) {
    float4 w = *(const float4*)&cw[(c + i) * 4];
    wf[i][0] = w.x; wf[i][1] = w.y; wf[i][2] = w.z; wf[i][3] = w.w;
  }
  float a[4] = {0.f, 0.f, 0.f, 0.f};
#pragma unroll
  for (int j = 0; j < 4; ++j) {
    const int tt = t - 3 + j;
    if (tt >= 0) {
      short4v iv = *(const short4v*)(rowp + ((ptrdiff_t)j - 3) * CD_);
#pragma unroll
      for (int i = 0; i < 4; ++i) a[i] += b2f((ushort_t)iv[i]) * wf[i][j];
    }
  }
  float4 o;
  o.x = a[0] / (1.f + expf(-a[0]));
  o.y = a[1] / (1.f + expf(-a[1]));
  o.z = a[2] / (1.f + expf(-a[2]));
  o.w = a[3] / (1.f + expf(-a[3]));
  *(float4*)(act + (size_t)bt * CD_ + c) = o;
}

// ---------------------------------------------------------------------------
// L2-normalize q (with HD^-1/2 scale) and k rows in-place (fp32). Wave per row.
// ---------------------------------------------------------------------------
__global__ __launch_bounds__(256)
void k_l2norm_qk(float* __restrict__ act) {
  const int row  = blockIdx.x * 4 + (threadIdx.x >> 6);  // B*T*16 rows
  const int lane = threadIdx.x & 63;
  const int bt = row >> 4, s = row & 15;
  float* p = act + (size_t)bt * CD_ + (s < 8 ? s * HD_ : KD_ + (s - 8) * HD_);
  float2 v = *(float2*)&p[lane * 2];
  float ss = v.x * v.x + v.y * v.y;
#pragma unroll
  for (int m = 1; m < 64; m <<= 1) ss += __shfl_xor(ss, m);
  float scale = 1.f / fmaxf(sqrtf(ss), 1e-12f);
  if (s < 8) scale *= 0.08838834764831845f;  // HD^-0.5
  v.x *= scale; v.y *= scale;
  *(float2*)&p[lane * 2] = v;
}

// ---------------------------------------------------------------------------
// Gated delta-rule recurrence. State columns are independent:
//   s_j <- d*s_j + beta*(v_j - d*(k.s_j))*k ,  o_j = q.s_j (post-update).
// Block = 1 wave = (b, head, 8 columns); 8 lanes/col, 16 state rows/lane.
// 8-deep register prefetch ring hides L3 latency (~600cy) behind 8 step-chains.
// All slot indices are compile-time (macros) so buffers stay in VGPRs.
// ---------------------------------------------------------------------------
__global__ __launch_bounds__(64, 1)
void k_recur(const float* __restrict__ act, const float* __restrict__ beta,
             const float* __restrict__ decay, float* __restrict__ ob) {
  const int gid = blockIdx.x;            // B*NV*16
  const int grp = gid & 15;
  const int h   = (gid >> 4) & 15;
  const int b   = gid >> 8;
  const int l   = threadIdx.x;
  const int cl = l >> 3, ro = l & 7;
  const int col = grp * 8 + cl;
  const int hq  = h >> 1;                // GQA: v-head h uses q/k head h/2
  const float* baseQ = act + (size_t)b * T_ * CD_ + hq * HD_ + ro * 16;
  const float* baseK = baseQ + KD_;
  const float* baseV = act + (size_t)b * T_ * CD_ + 2 * KD_ + h * HD_ + col;
  const float* bp = beta  + (size_t)b * T_ * NV_ + h;
  const float* dp = decay + (size_t)b * T_ * NV_ + h;
  float* op = ob + ((size_t)b * T_ * NV_ + h) * HD_ + col;

  float s[16];
#pragma unroll
  for (int j = 0; j < 16; ++j) s[j] = 0.f;

  float4 kb[8][4], qb[8][4];
  float vv[8], bb[8], dd[8];

#define LDSLOT(SL, TT) {                                                    \
    const int tc = ((TT) < T_) ? (TT) : (T_ - 1);                           \
    const float* rk = baseK + (size_t)tc * CD_;                             \
    const float* rq = baseQ + (size_t)tc * CD_;                             \
    kb[SL][0] = *(const float4*)(rk);      kb[SL][1] = *(const float4*)(rk + 4);  \
    kb[SL][2] = *(const float4*)(rk + 8);  kb[SL][3] = *(const float4*)(rk + 12); \
    qb[SL][0] = *(const float4*)(rq);      qb[SL][1] = *(const float4*)(rq + 4);  \
    qb[SL][2] = *(const float4*)(rq + 8);  qb[SL][3] = *(const float4*)(rq + 12); \
    vv[SL] = baseV[(size_t)tc * CD_];                                       \
    bb[SL] = bp[(size_t)tc * NV_];                                          \
    dd[SL] = dp[(size_t)tc * NV_];                                          \
  }

#define STEP(SL, TT) {                                                      \
    float pr[16];                                                           \
    _Pragma("unroll") for (int i = 0; i < 4; ++i) {                         \
      pr[4*i+0] = kb[SL][i].x * s[4*i+0];                                   \
      pr[4*i+1] = kb[SL][i].y * s[4*i+1];                                   \
      pr[4*i+2] = kb[SL][i].z * s[4*i+2];                                   \
      pr[4*i+3] = kb[SL][i].w * s[4*i+3];                                   \
    }                                                                       \
    _Pragma("unroll") for (int j = 0; j < 8; ++j) pr[j] += pr[j+8];         \
    _Pragma("unroll") for (int j = 0; j < 4; ++j) pr[j] += pr[j+4];         \
    pr[0] += pr[2]; pr[1] += pr[3];                                         \
    float kts = pr[0] + pr[1];                                              \
    kts += __shfl_xor(kts, 1); kts += __shfl_xor(kts, 2); kts += __shfl_xor(kts, 4); \
    const float w = bb[SL] * (vv[SL] - dd[SL] * kts);                       \
    _Pragma("unroll") for (int i = 0; i < 4; ++i) {                         \
      s[4*i+0] = dd[SL] * s[4*i+0] + kb[SL][i].x * w;                       \
      s[4*i+1] = dd[SL] * s[4*i+1] + kb[SL][i].y * w;                       \
      s[4*i+2] = dd[SL] * s[4*i+2] + kb[SL][i].z * w;                       \
      s[4*i+3] = dd[SL] * s[4*i+3] + kb[SL][i].w * w;                       \
    }                                                                       \
    float qr[16];                                                           \
    _Pragma("unroll") for (int i = 0; i < 4; ++i) {                         \
      qr[4*i+0] = qb[SL][i].x * s[4*i+0];                                   \
      qr[4*i+1] = qb[SL][i].y * s[4*i+1];                                   \
      qr[4*i+2] = qb[SL][i].z * s[4*i+2];                                   \
      qr[4*i+3] = qb[SL][i].w * s[4*i+3];                                   \
    }                                                                       \
    _Pragma("unroll") for (int j = 0; j < 8; ++j) qr[j] += qr[j+8];         \
    _Pragma("unroll") for (int j = 0; j < 4; ++j) qr[j] += qr[j+4];         \
    qr[0] += qr[2]; qr[1] += qr[3];                                         \
    float ov = qr[0] + qr[1];                                               \
    ov += __shfl_xor(ov, 1); ov += __shfl_xor(ov, 2); ov += __shfl_xor(ov, 4); \
    if (ro == 0) op[(size_t)(TT) * (NV_ * HD_)] = ov;                       \
  }

  LDSLOT(0, 0) LDSLOT(1, 1) LDSLOT(2, 2) LDSLOT(3, 3)
  LDSLOT(4, 4) LDSLOT(5, 5) LDSLOT(6, 6) LDSLOT(7, 7)

  for (int t = 0; t < T_; t += 8) {
    STEP(0, t)     LDSLOT(0, t + 8)
    STEP(1, t + 1) LDSLOT(1, t + 9)
    STEP(2, t + 2) LDSLOT(2, t + 10)
    STEP(3, t + 3) LDSLOT(3, t + 11)
    STEP(4, t + 4) LDSLOT(4, t + 12)
    STEP(5, t + 5) LDSLOT(5, t + 13)
    STEP(6, t + 6) LDSLOT(6, t + 14)
    STEP(7, t + 7) LDSLOT(7, t + 15)
  }
#undef LDSLOT
#undef STEP
}

// ---------------------------------------------------------------------------
// Gated RMSNorm: out = (o/rms(o)) * norm_w * silu(z); fp32 o, bf16 z,
// fp32 norm_w -> bf16 out (final GEMM operand).
// ---------------------------------------------------------------------------
__global__ __launch_bounds__(256)
void k_gate_rms(const float* __restrict__ ob, const ushort_t* __restrict__ z,
                const float* __restrict__ nw, ushort_t* __restrict__ og) {
  const int row  = blockIdx.x * 4 + (threadIdx.x >> 6);  // B*T*NV rows
  const int lane = threadIdx.x & 63;
  const float* op = ob + (size_t)row * HD_;
  float2 v = *(const float2*)&op[lane * 2];
  float ss = v.x * v.x + v.y * v.y;
#pragma unroll
  for (int m = 1; m < 64; m <<= 1) ss += __shfl_xor(ss, m);
  const float r = 1.f / sqrtf(ss * (1.f / HD_) + 1e-6f);
  unsigned int zz = *(const unsigned int*)&z[(size_t)row * HD_ + lane * 2];
  float z0 = b2f((ushort_t)(zz & 0xffffu));
  float z1 = b2f((ushort_t)(zz >> 16));
  float2 w = *(const float2*)&nw[lane * 2];
  float g0 = z0 / (1.f + expf(-z0));
  float g1 = z1 / (1.f + expf(-z1));
  unsigned int pack = (unsigned int)f2b(v.x * r * w.x * g0)
                    | ((unsigned int)f2b(v.y * r * w.y * g1) << 16);
  *(unsigned int*)&og[(size_t)row * HD_ + lane * 2] = pack;
}

// ---------------------------------------------------------------------------
extern "C" void kernel_launch(void* const* d_in, const int* in_sizes, int n_in,
                              void* d_out, int out_size, void* d_ws, size_t ws_size,
                              hipStream_t stream) {
  const float* x    = (const float*)d_in[0];
  const float* Wqkv = (const float*)d_in[1];
  const float* Wz   = (const float*)d_in[2];
  const float* Wb   = (const float*)d_in[3];
  const float* Wa   = (const float*)d_in[4];
  const float* cw   = (const float*)d_in[5];
  const float* dtb  = (const float*)d_in[6];
  const float* alog = (const float*)d_in[7];
  const float* nw   = (const float*)d_in[8];
  const float* Wout = (const float*)d_in[9];

  char* p = (char*)d_ws;
  ushort_t* qkv_raw = (ushort_t*)p; p += (size_t)B_ * T_ * CD_ * 2;       // 33.5 MB
  ushort_t* zbuf    = (ushort_t*)p; p += (size_t)B_ * T_ * VD_ * 2;       // 16.8 MB
  char*     actBase = p;
  float*    act     = (float*)p;    p += (size_t)B_ * T_ * CD_ * 4;       // 67.1 MB
  float*    betaB   = (float*)p;    p += (size_t)B_ * T_ * NV_ * 4;
  float*    decayB  = (float*)p;    p += (size_t)B_ * T_ * NV_ * 4;
  float*    obuf    = (float*)p;    p += (size_t)B_ * T_ * NV_ * HD_ * 4; // 33.5 MB
  ushort_t* WoutB   = (ushort_t*)p; p += (size_t)HID_ * VD_ * 2;          // 8.4 MB
  // bf16 cast buffers aliased into act region (dead before conv writes act):
  ushort_t* xB    = (ushort_t*)(actBase);                                 // 16.8 MB
  ushort_t* WqkvB = (ushort_t*)(actBase + (size_t)B_ * T_ * HID_ * 2);    // 16.8 MB
  ushort_t* WzB   = (ushort_t*)(actBase + (size_t)B_ * T_ * HID_ * 2
                                        + (size_t)CD_ * HID_ * 2);        // 8.4 MB
  ushort_t* outg  = qkv_raw;        // reuse: qkv_raw dead after conv

  const int M = B_ * T_;  // 4096

  hipLaunchKernelGGL(k_cast_bf16, dim3(M * HID_ / 4 / 256), dim3(256), 0, stream,
                     x, xB, M * HID_ / 4);
  hipLaunchKernelGGL(k_cast_bf16, dim3(CD_ * HID_ / 4 / 256), dim3(256), 0, stream,
                     Wqkv, WqkvB, CD_ * HID_ / 4);
  hipLaunchKernelGGL(k_cast_bf16, dim3(VD_ * HID_ / 4 / 256), dim3(256), 0, stream,
                     Wz, WzB, VD_ * HID_ / 4);
  hipLaunchKernelGGL(k_cast_bf16, dim3(HID_ * VD_ / 4 / 256), dim3(256), 0, stream,
                     Wout, WoutB, HID_ * VD_ / 4);

  hipLaunchKernelGGL(k_gemm_bt<ushort_t>, dim3(CD_ / 128, M / 128), dim3(256), 0, stream,
                     xB, WqkvB, qkv_raw, M, CD_, HID_);
  hipLaunchKernelGGL(k_gemm_bt<ushort_t>, dim3(VD_ / 128, M / 128), dim3(256), 0, stream,
                     xB, WzB, zbuf, M, VD_, HID_);
  hipLaunchKernelGGL(k_proj_ba, dim3(M), dim3(256), 0, stream,
                     x, Wb, Wa, dtb, alog, betaB, decayB);
  hipLaunchKernelGGL(k_conv_silu, dim3(M * CD_ / 4 / 256), dim3(256), 0, stream,
                     qkv_raw, cw, act);
  hipLaunchKernelGGL(k_l2norm_qk, dim3(M * 16 / 4), dim3(256), 0, stream, act);
  hipLaunchKernelGGL(k_recur, dim3(B_ * NV_ * 16), dim3(64), 0, stream,
                     act, betaB, decayB, obuf);
  hipLaunchKernelGGL(k_gate_rms, dim3(M * NV_ / 4), dim3(256), 0, stream,
                     obuf, zbuf, nw, outg);
  hipLaunchKernelGGL(k_gemm_bt<float>, dim3(HID_ / 128, M / 128), dim3(256), 0, stream,
                     outg, WoutB, (float*)d_out, M, HID_, VD_);
}

// Round 4
// 1365.224 us; speedup vs baseline: 1.1744x; 1.0973x over previous
//
#include <hip/hip_runtime.h>
#include <cstdint>
#include <cstddef>

// GatedDeltaNet forward, MI355X/gfx950.
// Inputs/outputs are fp32 (reference computes in jnp.float32).
// Pipeline: cast(x,Wqkv,Wz,Wout -> bf16) -> [gemm qkv] [gemm z] [proj b/a]
//           -> conv1d+silu (fp32) -> l2norm q,k -> gated delta-rule recurrence
//           -> gated RMSNorm*silu(z) (bf16 out) -> [gemm out -> fp32 d_out].
// R3: k_recur uses global_load_lds double-buffered tile staging (16 steps/tile)
//     — R2's register prefetch ring was collapsed by the compiler (VGPR=164
//     proved loads were sunk to use; still 1 load-latency per step).

typedef unsigned short ushort_t;
typedef __attribute__((ext_vector_type(8))) __bf16 bf16x8;
typedef __attribute__((ext_vector_type(4))) float f32x4;
typedef __attribute__((ext_vector_type(4))) short short4v;

#define B_   2
#define T_   2048
#define HID_ 2048
#define NK_  8
#define NV_  16
#define HD_  128
#define KD_  1024
#define VD_  2048
#define CD_  4096

__device__ __forceinline__ float b2f(ushort_t u) {
  union { unsigned int i; float f; } v; v.i = ((unsigned int)u) << 16; return v.f;
}
__device__ __forceinline__ ushort_t f2b(float f) {   // RNE bf16 round
  unsigned int x = __builtin_bit_cast(unsigned int, f);
  unsigned int r = x + 0x7fffu + ((x >> 16) & 1u);
  return (ushort_t)(r >> 16);
}

// ---------------------------------------------------------------------------
// fp32 -> bf16 cast (vectorized: 4 elems/thread)
// ---------------------------------------------------------------------------
__global__ __launch_bounds__(256)
void k_cast_bf16(const float* __restrict__ in, ushort_t* __restrict__ out, int n4) {
  const int i = blockIdx.x * 256 + threadIdx.x;
  if (i >= n4) return;
  float4 v = *(const float4*)(in + (size_t)i * 4);
  short4v o;
  o[0] = (short)f2b(v.x); o[1] = (short)f2b(v.y);
  o[2] = (short)f2b(v.z); o[3] = (short)f2b(v.w);
  *(short4v*)(out + (size_t)i * 4) = o;
}

// ---------------------------------------------------------------------------
// GEMM: C[m,n] = sum_k A[m,k] * B[n,k]   (A: MxK row-major bf16, B: NxK bf16)
// m97 structure: 128x128 tile, BK=32, 4 waves, global_load_lds width 16.
// ---------------------------------------------------------------------------
template <typename OutT>
__global__ __launch_bounds__(256)
void k_gemm_bt(const ushort_t* __restrict__ A, const ushort_t* __restrict__ Bw,
               OutT* __restrict__ C, int M, int N, int K) {
  __shared__ alignas(16) ushort_t As[128 * 32];
  __shared__ alignas(16) ushort_t Bs[128 * 32];
  const int tid  = threadIdx.x;
  const int lane = tid & 63;
  const int wave = tid >> 6;
  const int wr = wave >> 1, wc = wave & 1;
  const size_t row0 = (size_t)blockIdx.y * 128;
  const size_t col0 = (size_t)blockIdx.x * 128;

  f32x4 acc[4][4] = {};
  const int fr = lane & 15;            // fragment row/col
  const int ks = (lane >> 4) * 8;      // k-slice within BK=32

  for (int kt = 0; kt < K; kt += 32) {
    __syncthreads();                   // LDS reads of prev tile done
#pragma unroll
    for (int ch = 0; ch < 2; ++ch) {
      const int li  = ch * 256 + tid;  // 16B-unit index, 512 per 8KB tile
      const int row = li >> 2;
      const int cp  = li & 3;
      const ushort_t* ga = A  + (row0 + row) * (size_t)K + kt + cp * 8;
      const ushort_t* gb = Bw + (col0 + row) * (size_t)K + kt + cp * 8;
      ushort_t* la = As + ((li >> 6) << 9);  // wave-uniform 1KB chunk base
      ushort_t* lb = Bs + ((li >> 6) << 9);
      __builtin_amdgcn_global_load_lds(
          (const __attribute__((address_space(1))) unsigned int*)ga,
          (__attribute__((address_space(3))) unsigned int*)la, 16, 0, 0);
      __builtin_amdgcn_global_load_lds(
          (const __attribute__((address_space(1))) unsigned int*)gb,
          (__attribute__((address_space(3))) unsigned int*)lb, 16, 0, 0);
    }
    __syncthreads();                   // vmcnt(0) drained by compiler

    bf16x8 af[4], bfv[4];
#pragma unroll
    for (int m = 0; m < 4; ++m)
      af[m]  = *(const bf16x8*)&As[(wr * 64 + m * 16 + fr) * 32 + ks];
#pragma unroll
    for (int n = 0; n < 4; ++n)
      bfv[n] = *(const bf16x8*)&Bs[(wc * 64 + n * 16 + fr) * 32 + ks];
#pragma unroll
    for (int m = 0; m < 4; ++m)
#pragma unroll
      for (int n = 0; n < 4; ++n)
        acc[m][n] = __builtin_amdgcn_mfma_f32_16x16x32_bf16(af[m], bfv[n], acc[m][n], 0, 0, 0);
  }

  const int r4 = (lane >> 4) * 4;      // C/D: col=lane&15, row=(lane>>4)*4+reg
#pragma unroll
  for (int m = 0; m < 4; ++m)
#pragma unroll
    for (int n = 0; n < 4; ++n)
#pragma unroll
      for (int j = 0; j < 4; ++j) {
        const size_t row = row0 + wr * 64 + m * 16 + r4 + j;
        const size_t col = col0 + wc * 64 + n * 16 + fr;
        if constexpr (sizeof(OutT) == 4)
          C[row * (size_t)N + col] = acc[m][n][j];
        else
          C[row * (size_t)N + col] = (OutT)f2b(acc[m][n][j]);
      }
}

// ---------------------------------------------------------------------------
// b/a projection + activation (fp32 in): beta = sigmoid(x@Wb^T),
// decay = exp(-exp(A_log) * softplus(x@Wa^T + dt_bias)). One block per (b,t).
// ---------------------------------------------------------------------------
__global__ __launch_bounds__(256)
void k_proj_ba(const float* __restrict__ x, const float* __restrict__ Wb,
               const float* __restrict__ Wa, const float* __restrict__ dtb,
               const float* __restrict__ alog,
               float* __restrict__ beta, float* __restrict__ decay) {
  __shared__ float xs[HID_];
  __shared__ float part[32][8];
  const int bt = blockIdx.x, tid = threadIdx.x;
  const float* xr = x + (size_t)bt * HID_;
  *(float4*)&xs[tid * 8]     = *(const float4*)&xr[tid * 8];
  *(float4*)&xs[tid * 8 + 4] = *(const float4*)&xr[tid * 8 + 4];
  __syncthreads();
  const int o = tid >> 3, seg = tid & 7;
  const float* W = (o < 16) ? (Wb + (size_t)o * HID_) : (Wa + (size_t)(o - 16) * HID_);
  float s = 0.f;
  for (int k = seg * 256; k < seg * 256 + 256; k += 4) {
    float4 wv = *(const float4*)&W[k];
    float4 xv = *(const float4*)&xs[k];
    s += wv.x * xv.x + wv.y * xv.y + wv.z * xv.z + wv.w * xv.w;
  }
  part[o][seg] = s;
  __syncthreads();
  if (tid < 32) {
    float tsum = 0.f;
#pragma unroll
    for (int i = 0; i < 8; ++i) tsum += part[tid][i];
    if (tid < 16) {
      beta[(size_t)bt * NV_ + tid] = 1.f / (1.f + expf(-tsum));
    } else {
      const int h = tid - 16;
      float aa = tsum + dtb[h];
      float sp = (aa > 20.f) ? aa : log1pf(expf(aa));
      decay[(size_t)bt * NV_ + h] = expf(-expf(alog[h]) * sp);
    }
  }
}

// ---------------------------------------------------------------------------
// Depthwise causal conv1d (K=4, left zero-pad) + silu, bf16 in -> fp32 out.
// ---------------------------------------------------------------------------
__global__ __launch_bounds__(256)
void k_conv_silu(const ushort_t* __restrict__ qkv, const float* __restrict__ cw,
                 float* __restrict__ act) {
  const unsigned idx = blockIdx.x * 256u + threadIdx.x;  // B*T*CD/4 total
  const unsigned c4  = idx & (CD_ / 4 - 1);
  const unsigned bt  = idx >> 10;                        // / (CD_/4)
  const int t = bt & (T_ - 1);
  const int c = c4 * 4;
  const ushort_t* rowp = qkv + (size_t)bt * CD_ + c;
  float wf[4][4];
#pragma unroll
  for (int i = 0; i < 4; ++i) {
    float4 w = *(const float4*)&cw[(c + i) * 4];
    wf[i][0] = w.x; wf[i][1] = w.y; wf[i][2] = w.z; wf[i][3] = w.w;
  }
  float a[4] = {0.f, 0.f, 0.f, 0.f};
#pragma unroll
  for (int j = 0; j < 4; ++j) {
    const int tt = t - 3 + j;
    if (tt >= 0) {
      short4v iv = *(const short4v*)(rowp + ((ptrdiff_t)j - 3) * CD_);
#pragma unroll
      for (int i = 0; i < 4; ++i) a[i] += b2f((ushort_t)iv[i]) * wf[i][j];
    }
  }
  float4 o;
  o.x = a[0] / (1.f + expf(-a[0]));
  o.y = a[1] / (1.f + expf(-a[1]));
  o.z = a[2] / (1.f + expf(-a[2]));
  o.w = a[3] / (1.f + expf(-a[3]));
  *(float4*)(act + (size_t)bt * CD_ + c) = o;
}

// ---------------------------------------------------------------------------
// L2-normalize q (with HD^-1/2 scale) and k rows in-place (fp32). Wave per row.
// ---------------------------------------------------------------------------
__global__ __launch_bounds__(256)
void k_l2norm_qk(float* __restrict__ act) {
  const int row  = blockIdx.x * 4 + (threadIdx.x >> 6);  // B*T*16 rows
  const int lane = threadIdx.x & 63;
  const int bt = row >> 4, s = row & 15;
  float* p = act + (size_t)bt * CD_ + (s < 8 ? s * HD_ : KD_ + (s - 8) * HD_);
  float2 v = *(float2*)&p[lane * 2];
  float ss = v.x * v.x + v.y * v.y;
#pragma unroll
  for (int m = 1; m < 64; m <<= 1) ss += __shfl_xor(ss, m);
  float scale = 1.f / fmaxf(sqrtf(ss), 1e-12f);
  if (s < 8) scale *= 0.08838834764831845f;  // HD^-0.5
  v.x *= scale; v.y *= scale;
  *(float2*)&p[lane * 2] = v;
}

// ---------------------------------------------------------------------------
// Gated delta-rule recurrence. State columns are independent:
//   s_j <- d*s_j + beta*(v_j - d*(k.s_j))*k ,  o_j = q.s_j (post-update).
// Block = 1 wave = (b, head, 8 columns); 8 lanes/col, 16 state rows/lane.
// R3: k/q staged to LDS in 16-step tiles via global_load_lds (double-buffered);
// one vmcnt(0) fence per tile. v/beta/decay register-staged per tile and
// redistributed per-step with __shfl (off the recurrence critical path).
// ---------------------------------------------------------------------------
__global__ __launch_bounds__(64, 1)
void k_recur(const float* __restrict__ act, const float* __restrict__ beta,
             const float* __restrict__ decay, float* __restrict__ ob) {
  __shared__ alignas(16) float kqs[2][2][16][128];   // [buf][k/q][t][d] = 32 KB
  const int gid = blockIdx.x;            // B*NV*16
  const int grp = gid & 15;
  const int h   = (gid >> 4) & 15;
  const int b   = gid >> 8;
  const int l   = threadIdx.x;
  const int cl = l >> 3, ro = l & 7;
  const int hq  = h >> 1;                // GQA: v-head h uses q/k head h/2
  const float* baseQ = act + (size_t)b * T_ * CD_ + hq * HD_;
  const float* baseK = baseQ + KD_;
  const float* baseV = act + (size_t)b * T_ * CD_ + 2 * KD_ + h * HD_ + grp * 8;
  const float* bp = beta  + (size_t)b * T_ * NV_ + h;
  const float* dp = decay + (size_t)b * T_ * NV_ + h;
  float* op = ob + ((size_t)b * T_ * NV_ + h) * HD_ + grp * 8 + cl;

  float s[16];
#pragma unroll
  for (int j = 0; j < 16; ++j) s[j] = 0.f;

  // Stage 16 timesteps of k and q rows into LDS buf (wave-uniform LDS base;
  // lane l writes base + l*16B => rows i*2 (lanes 0-31) and i*2+1 (lanes 32-63)).
#define STAGE(BUF, TILE) {                                                   \
    const int tb_ = (TILE) * 16;                                             \
    _Pragma("unroll") for (int i_ = 0; i_ < 8; ++i_) {                       \
      int t_ = tb_ + i_ * 2 + (l >> 5);                                      \
      if (t_ > T_ - 1) t_ = T_ - 1;                                          \
      const float* sk_ = baseK + (size_t)t_ * CD_ + (l & 31) * 4;            \
      const float* sq_ = baseQ + (size_t)t_ * CD_ + (l & 31) * 4;            \
      __builtin_amdgcn_global_load_lds(                                      \
          (const __attribute__((address_space(1))) unsigned int*)sk_,        \
          (__attribute__((address_space(3))) unsigned int*)&kqs[BUF][0][i_ * 2][0], \
          16, 0, 0);                                                         \
      __builtin_amdgcn_global_load_lds(                                      \
          (const __attribute__((address_space(1))) unsigned int*)sq_,        \
          (__attribute__((address_space(3))) unsigned int*)&kqs[BUF][1][i_ * 2][0], \
          16, 0, 0);                                                         \
    }                                                                        \
  }

  // Per-tile scalar staging: lane l holds v[tb+(l>>3)][col l&7] (V0) and
  // v[tb+8+(l>>3)][col l&7] (V1); beta/decay for t = tb + (l&15).
#define LDSC(V0, V1, BB, DD, TILE) {                                         \
    const int tb_ = (TILE) * 16;                                             \
    int tv_ = tb_ + (l >> 3); if (tv_ > T_ - 1) tv_ = T_ - 1;                \
    int tw_ = tv_ + 8;        if (tw_ > T_ - 1) tw_ = T_ - 1;                \
    V0 = baseV[(size_t)tv_ * CD_ + (l & 7)];                                 \
    V1 = baseV[(size_t)tw_ * CD_ + (l & 7)];                                 \
    int td_ = tb_ + (l & 15); if (td_ > T_ - 1) td_ = T_ - 1;                \
    BB = bp[(size_t)td_ * NV_];                                              \
    DD = dp[(size_t)td_ * NV_];                                              \
  }

#define STEP1(BUF, TS, TT, VREG, BBR, DDR) {                                 \
    const float* kp_ = &kqs[BUF][0][TS][ro * 16];                            \
    const float* qp_ = &kqs[BUF][1][TS][ro * 16];                            \
    float4 k0 = *(const float4*)(kp_ +  0);                                  \
    float4 k1 = *(const float4*)(kp_ +  4);                                  \
    float4 k2 = *(const float4*)(kp_ +  8);                                  \
    float4 k3 = *(const float4*)(kp_ + 12);                                  \
    float4 q0 = *(const float4*)(qp_ +  0);                                  \
    float4 q1 = *(const float4*)(qp_ +  4);                                  \
    float4 q2 = *(const float4*)(qp_ +  8);                                  \
    float4 q3 = *(const float4*)(qp_ + 12);                                  \
    const float dd = __shfl(DDR, (TS));                                      \
    const float bb = __shfl(BBR, (TS));                                      \
    const float vv = __shfl(VREG, (((TS) & 7) << 3) | cl);                   \
    float p0 = k0.x * s[0]  + k0.y * s[1];                                   \
    float p1 = k0.z * s[2]  + k0.w * s[3];                                   \
    float p2 = k1.x * s[4]  + k1.y * s[5];                                   \
    float p3 = k1.z * s[6]  + k1.w * s[7];                                   \
    float p4 = k2.x * s[8]  + k2.y * s[9];                                   \
    float p5 = k2.z * s[10] + k2.w * s[11];                                  \
    float p6 = k3.x * s[12] + k3.y * s[13];                                  \
    float p7 = k3.z * s[14] + k3.w * s[15];                                  \
    p0 += p1; p2 += p3; p4 += p5; p6 += p7;                                  \
    p0 += p2; p4 += p6;                                                      \
    float kts = p0 + p4;                                                     \
    kts += __shfl_xor(kts, 1); kts += __shfl_xor(kts, 2);                    \
    kts += __shfl_xor(kts, 4);                                               \
    const float w = bb * (vv - dd * kts);                                    \
    s[0]  = dd * s[0]  + k0.x * w;  s[1]  = dd * s[1]  + k0.y * w;           \
    s[2]  = dd * s[2]  + k0.z * w;  s[3]  = dd * s[3]  + k0.w * w;           \
    s[4]  = dd * s[4]  + k1.x * w;  s[5]  = dd * s[5]  + k1.y * w;           \
    s[6]  = dd * s[6]  + k1.z * w;  s[7]  = dd * s[7]  + k1.w * w;           \
    s[8]  = dd * s[8]  + k2.x * w;  s[9]  = dd * s[9]  + k2.y * w;           \
    s[10] = dd * s[10] + k2.z * w;  s[11] = dd * s[11] + k2.w * w;           \
    s[12] = dd * s[12] + k3.x * w;  s[13] = dd * s[13] + k3.y * w;           \
    s[14] = dd * s[14] + k3.z * w;  s[15] = dd * s[15] + k3.w * w;           \
    float r0 = q0.x * s[0]  + q0.y * s[1];                                   \
    float r1 = q0.z * s[2]  + q0.w * s[3];                                   \
    float r2 = q1.x * s[4]  + q1.y * s[5];                                   \
    float r3 = q1.z * s[6]  + q1.w * s[7];                                   \
    float r4 = q2.x * s[8]  + q2.y * s[9];                                   \
    float r5 = q2.z * s[10] + q2.w * s[11];                                  \
    float r6 = q3.x * s[12] + q3.y * s[13];                                  \
    float r7 = q3.z * s[14] + q3.w * s[15];                                  \
    r0 += r1; r2 += r3; r4 += r5; r6 += r7;                                  \
    r0 += r2; r4 += r6;                                                      \
    float ov = r0 + r4;                                                      \
    ov += __shfl_xor(ov, 1); ov += __shfl_xor(ov, 2);                        \
    ov += __shfl_xor(ov, 4);                                                 \
    if (ro == 0) op[(size_t)(TT) * (NV_ * HD_)] = ov;                        \
  }

#define STEPS16(BUF, TILE, V0, V1, BB, DD) {                                 \
    const int tt0_ = (TILE) * 16;                                            \
    STEP1(BUF, 0,  tt0_ + 0,  V0, BB, DD)                                    \
    STEP1(BUF, 1,  tt0_ + 1,  V0, BB, DD)                                    \
    STEP1(BUF, 2,  tt0_ + 2,  V0, BB, DD)                                    \
    STEP1(BUF, 3,  tt0_ + 3,  V0, BB, DD)                                    \
    STEP1(BUF, 4,  tt0_ + 4,  V0, BB, DD)                                    \
    STEP1(BUF, 5,  tt0_ + 5,  V0, BB, DD)                                    \
    STEP1(BUF, 6,  tt0_ + 6,  V0, BB, DD)                                    \
    STEP1(BUF, 7,  tt0_ + 7,  V0, BB, DD)                                    \
    STEP1(BUF, 8,  tt0_ + 8,  V1, BB, DD)                                    \
    STEP1(BUF, 9,  tt0_ + 9,  V1, BB, DD)                                    \
    STEP1(BUF, 10, tt0_ + 10, V1, BB, DD)                                    \
    STEP1(BUF, 11, tt0_ + 11, V1, BB, DD)                                    \
    STEP1(BUF, 12, tt0_ + 12, V1, BB, DD)                                    \
    STEP1(BUF, 13, tt0_ + 13, V1, BB, DD)                                    \
    STEP1(BUF, 14, tt0_ + 14, V1, BB, DD)                                    \
    STEP1(BUF, 15, tt0_ + 15, V1, BB, DD)                                    \
  }

  float vA0, vA1, bbA, ddA, vB0, vB1, bbB, ddB;
  STAGE(0, 0)
  LDSC(vA0, vA1, bbA, ddA, 0)

  for (int tile = 0; tile < T_ / 16; tile += 2) {
    // wait tile (buf0) staged; then prefetch tile+1 into buf1
    asm volatile("s_waitcnt vmcnt(0)" ::: "memory");
    STAGE(1, tile + 1)
    LDSC(vB0, vB1, bbB, ddB, tile + 1)
    STEPS16(0, tile, vA0, vA1, bbA, ddA)
    // wait tile+1 (buf1) staged; then prefetch tile+2 into buf0
    asm volatile("s_waitcnt vmcnt(0)" ::: "memory");
    if (tile + 2 < T_ / 16) {
      STAGE(0, tile + 2)
      LDSC(vA0, vA1, bbA, ddA, tile + 2)
    }
    STEPS16(1, tile + 1, vB0, vB1, bbB, ddB)
  }
#undef STAGE
#undef LDSC
#undef STEP1
#undef STEPS16
}

// ---------------------------------------------------------------------------
// Gated RMSNorm: out = (o/rms(o)) * norm_w * silu(z); fp32 o, bf16 z,
// fp32 norm_w -> bf16 out (final GEMM operand).
// ---------------------------------------------------------------------------
__global__ __launch_bounds__(256)
void k_gate_rms(const float* __restrict__ ob, const ushort_t* __restrict__ z,
                const float* __restrict__ nw, ushort_t* __restrict__ og) {
  const int row  = blockIdx.x * 4 + (threadIdx.x >> 6);  // B*T*NV rows
  const int lane = threadIdx.x & 63;
  const float* op = ob + (size_t)row * HD_;
  float2 v = *(const float2*)&op[lane * 2];
  float ss = v.x * v.x + v.y * v.y;
#pragma unroll
  for (int m = 1; m < 64; m <<= 1) ss += __shfl_xor(ss, m);
  const float r = 1.f / sqrtf(ss * (1.f / HD_) + 1e-6f);
  unsigned int zz = *(const unsigned int*)&z[(size_t)row * HD_ + lane * 2];
  float z0 = b2f((ushort_t)(zz & 0xffffu));
  float z1 = b2f((ushort_t)(zz >> 16));
  float2 w = *(const float2*)&nw[lane * 2];
  float g0 = z0 / (1.f + expf(-z0));
  float g1 = z1 / (1.f + expf(-z1));
  unsigned int pack = (unsigned int)f2b(v.x * r * w.x * g0)
                    | ((unsigned int)f2b(v.y * r * w.y * g1) << 16);
  *(unsigned int*)&og[(size_t)row * HD_ + lane * 2] = pack;
}

// ---------------------------------------------------------------------------
extern "C" void kernel_launch(void* const* d_in, const int* in_sizes, int n_in,
                              void* d_out, int out_size, void* d_ws, size_t ws_size,
                              hipStream_t stream) {
  const float* x    = (const float*)d_in[0];
  const float* Wqkv = (const float*)d_in[1];
  const float* Wz   = (const float*)d_in[2];
  const float* Wb   = (const float*)d_in[3];
  const float* Wa   = (const float*)d_in[4];
  const float* cw   = (const float*)d_in[5];
  const float* dtb  = (const float*)d_in[6];
  const float* alog = (const float*)d_in[7];
  const float* nw   = (const float*)d_in[8];
  const float* Wout = (const float*)d_in[9];

  char* p = (char*)d_ws;
  ushort_t* qkv_raw = (ushort_t*)p; p += (size_t)B_ * T_ * CD_ * 2;       // 33.5 MB
  ushort_t* zbuf    = (ushort_t*)p; p += (size_t)B_ * T_ * VD_ * 2;       // 16.8 MB
  char*     actBase = p;
  float*    act     = (float*)p;    p += (size_t)B_ * T_ * CD_ * 4;       // 67.1 MB
  float*    betaB   = (float*)p;    p += (size_t)B_ * T_ * NV_ * 4;
  float*    decayB  = (float*)p;    p += (size_t)B_ * T_ * NV_ * 4;
  float*    obuf    = (float*)p;    p += (size_t)B_ * T_ * NV_ * HD_ * 4; // 33.5 MB
  ushort_t* WoutB   = (ushort_t*)p; p += (size_t)HID_ * VD_ * 2;          // 8.4 MB
  // bf16 cast buffers aliased into act region (dead before conv writes act):
  ushort_t* xB    = (ushort_t*)(actBase);                                 // 16.8 MB
  ushort_t* WqkvB = (ushort_t*)(actBase + (size_t)B_ * T_ * HID_ * 2);    // 16.8 MB
  ushort_t* WzB   = (ushort_t*)(actBase + (size_t)B_ * T_ * HID_ * 2
                                        + (size_t)CD_ * HID_ * 2);        // 8.4 MB
  ushort_t* outg  = qkv_raw;        // reuse: qkv_raw dead after conv

  const int M = B_ * T_;  // 4096

  hipLaunchKernelGGL(k_cast_bf16, dim3(M * HID_ / 4 / 256), dim3(256), 0, stream,
                     x, xB, M * HID_ / 4);
  hipLaunchKernelGGL(k_cast_bf16, dim3(CD_ * HID_ / 4 / 256), dim3(256), 0, stream,
                     Wqkv, WqkvB, CD_ * HID_ / 4);
  hipLaunchKernelGGL(k_cast_bf16, dim3(VD_ * HID_ / 4 / 256), dim3(256), 0, stream,
                     Wz, WzB, VD_ * HID_ / 4);
  hipLaunchKernelGGL(k_cast_bf16, dim3(HID_ * VD_ / 4 / 256), dim3(256), 0, stream,
                     Wout, WoutB, HID_ * VD_ / 4);

  hipLaunchKernelGGL(k_gemm_bt<ushort_t>, dim3(CD_ / 128, M / 128), dim3(256), 0, stream,
                     xB, WqkvB, qkv_raw, M, CD_, HID_);
  hipLaunchKernelGGL(k_gemm_bt<ushort_t>, dim3(VD_ / 128, M / 128), dim3(256), 0, stream,
                     xB, WzB, zbuf, M, VD_, HID_);
  hipLaunchKernelGGL(k_proj_ba, dim3(M), dim3(256), 0, stream,
                     x, Wb, Wa, dtb, alog, betaB, decayB);
  hipLaunchKernelGGL(k_conv_silu, dim3(M * CD_ / 4 / 256), dim3(256), 0, stream,
                     qkv_raw, cw, act);
  hipLaunchKernelGGL(k_l2norm_qk, dim3(M * 16 / 4), dim3(256), 0, stream, act);
  hipLaunchKernelGGL(k_recur, dim3(B_ * NV_ * 16), dim3(64), 0, stream,
                     act, betaB, decayB, obuf);
  hipLaunchKernelGGL(k_gate_rms, dim3(M * NV_ / 4), dim3(256), 0, stream,
                     obuf, zbuf, nw, outg);
  hipLaunchKernelGGL(k_gemm_bt<float>, dim3(HID_ / 128, M / 128), dim3(256), 0, stream,
                     outg, WoutB, (float*)d_out, M, HID_, VD_);
}

// Round 5
// 840.098 us; speedup vs baseline: 1.9084x; 1.6251x over previous
//
#include <hip/hip_runtime.h>
#include <cstdint>
#include <cstddef>

// GatedDeltaNet forward, MI355X/gfx950.
// Inputs/outputs are fp32 (reference computes in jnp.float32).
// Pipeline: cast(x,Wqkv,Wz,Wout -> bf16) -> [gemm qkv] [gemm z] [proj b/a (g)]
//           -> conv1d+silu (fp32) -> l2norm q,k -> CHUNKED delta-rule (WY/MFMA)
//           -> gated RMSNorm*silu(z) (bf16 out) -> [gemm out -> fp32 d_out].
// R4->R5: scalar recurrence replaced by chunked parallel form (C=64):
//   u_t = beta_t(v_t - g_t k_t^T S0) - beta_t sum_{s<t}(g_t/g_s)(k_t.k_s)u_s
//   o_t = g_t q_t^T S0 + sum_{s<=t}(g_t/g_s)(q_t.k_s)u_s
//   S_C = g_C S0 + sum_s (g_C/g_s) k_s u_s^T
// MFMA for all dense phases; 2x32-step scalar forward substitution for the solve.

typedef unsigned short ushort_t;
typedef __attribute__((ext_vector_type(8))) __bf16 bf16x8;
typedef __attribute__((ext_vector_type(4))) float f32x4;
typedef __attribute__((ext_vector_type(4))) short short4v;

#define B_   2
#define T_   2048
#define HID_ 2048
#define NK_  8
#define NV_  16
#define HD_  128
#define KD_  1024
#define VD_  2048
#define CD_  4096

__device__ __forceinline__ float b2f(ushort_t u) {
  union { unsigned int i; float f; } v; v.i = ((unsigned int)u) << 16; return v.f;
}
__device__ __forceinline__ ushort_t f2b(float f) {   // RNE bf16 round
  unsigned int x = __builtin_bit_cast(unsigned int, f);
  unsigned int r = x + 0x7fffu + ((x >> 16) & 1u);
  return (ushort_t)(r >> 16);
}

// ---------------------------------------------------------------------------
// fp32 -> bf16 cast (vectorized: 4 elems/thread)
// ---------------------------------------------------------------------------
__global__ __launch_bounds__(256)
void k_cast_bf16(const float* __restrict__ in, ushort_t* __restrict__ out, int n4) {
  const int i = blockIdx.x * 256 + threadIdx.x;
  if (i >= n4) return;
  float4 v = *(const float4*)(in + (size_t)i * 4);
  short4v o;
  o[0] = (short)f2b(v.x); o[1] = (short)f2b(v.y);
  o[2] = (short)f2b(v.z); o[3] = (short)f2b(v.w);
  *(short4v*)(out + (size_t)i * 4) = o;
}

// ---------------------------------------------------------------------------
// GEMM: C[m,n] = sum_k A[m,k] * B[n,k]   (A: MxK row-major bf16, B: NxK bf16)
// m97 structure: 128x128 tile, BK=32, 4 waves, global_load_lds width 16.
// ---------------------------------------------------------------------------
template <typename OutT>
__global__ __launch_bounds__(256)
void k_gemm_bt(const ushort_t* __restrict__ A, const ushort_t* __restrict__ Bw,
               OutT* __restrict__ C, int M, int N, int K) {
  __shared__ alignas(16) ushort_t As[128 * 32];
  __shared__ alignas(16) ushort_t Bs[128 * 32];
  const int tid  = threadIdx.x;
  const int lane = tid & 63;
  const int wave = tid >> 6;
  const int wr = wave >> 1, wc = wave & 1;
  const size_t row0 = (size_t)blockIdx.y * 128;
  const size_t col0 = (size_t)blockIdx.x * 128;

  f32x4 acc[4][4] = {};
  const int fr = lane & 15;            // fragment row/col
  const int ks = (lane >> 4) * 8;      // k-slice within BK=32

  for (int kt = 0; kt < K; kt += 32) {
    __syncthreads();                   // LDS reads of prev tile done
#pragma unroll
    for (int ch = 0; ch < 2; ++ch) {
      const int li  = ch * 256 + tid;  // 16B-unit index, 512 per 8KB tile
      const int row = li >> 2;
      const int cp  = li & 3;
      const ushort_t* ga = A  + (row0 + row) * (size_t)K + kt + cp * 8;
      const ushort_t* gb = Bw + (col0 + row) * (size_t)K + kt + cp * 8;
      ushort_t* la = As + ((li >> 6) << 9);  // wave-uniform 1KB chunk base
      ushort_t* lb = Bs + ((li >> 6) << 9);
      __builtin_amdgcn_global_load_lds(
          (const __attribute__((address_space(1))) unsigned int*)ga,
          (__attribute__((address_space(3))) unsigned int*)la, 16, 0, 0);
      __builtin_amdgcn_global_load_lds(
          (const __attribute__((address_space(1))) unsigned int*)gb,
          (__attribute__((address_space(3))) unsigned int*)lb, 16, 0, 0);
    }
    __syncthreads();                   // vmcnt(0) drained by compiler

    bf16x8 af[4], bfv[4];
#pragma unroll
    for (int m = 0; m < 4; ++m)
      af[m]  = *(const bf16x8*)&As[(wr * 64 + m * 16 + fr) * 32 + ks];
#pragma unroll
    for (int n = 0; n < 4; ++n)
      bfv[n] = *(const bf16x8*)&Bs[(wc * 64 + n * 16 + fr) * 32 + ks];
#pragma unroll
    for (int m = 0; m < 4; ++m)
#pragma unroll
      for (int n = 0; n < 4; ++n)
        acc[m][n] = __builtin_amdgcn_mfma_f32_16x16x32_bf16(af[m], bfv[n], acc[m][n], 0, 0, 0);
  }

  const int r4 = (lane >> 4) * 4;      // C/D: col=lane&15, row=(lane>>4)*4+reg
#pragma unroll
  for (int m = 0; m < 4; ++m)
#pragma unroll
    for (int n = 0; n < 4; ++n)
#pragma unroll
      for (int j = 0; j < 4; ++j) {
        const size_t row = row0 + wr * 64 + m * 16 + r4 + j;
        const size_t col = col0 + wc * 64 + n * 16 + fr;
        if constexpr (sizeof(OutT) == 4)
          C[row * (size_t)N + col] = acc[m][n][j];
        else
          C[row * (size_t)N + col] = (OutT)f2b(acc[m][n][j]);
      }
}

// ---------------------------------------------------------------------------
// b/a projection + activation (fp32 in): beta = sigmoid(x@Wb^T),
// g = -exp(A_log) * softplus(x@Wa^T + dt_bias)   [log-decay, for chunk cumsum]
// ---------------------------------------------------------------------------
__global__ __launch_bounds__(256)
void k_proj_ba(const float* __restrict__ x, const float* __restrict__ Wb,
               const float* __restrict__ Wa, const float* __restrict__ dtb,
               const float* __restrict__ alog,
               float* __restrict__ beta, float* __restrict__ gout) {
  __shared__ float xs[HID_];
  __shared__ float part[32][8];
  const int bt = blockIdx.x, tid = threadIdx.x;
  const float* xr = x + (size_t)bt * HID_;
  *(float4*)&xs[tid * 8]     = *(const float4*)&xr[tid * 8];
  *(float4*)&xs[tid * 8 + 4] = *(const float4*)&xr[tid * 8 + 4];
  __syncthreads();
  const int o = tid >> 3, seg = tid & 7;
  const float* W = (o < 16) ? (Wb + (size_t)o * HID_) : (Wa + (size_t)(o - 16) * HID_);
  float s = 0.f;
  for (int k = seg * 256; k < seg * 256 + 256; k += 4) {
    float4 wv = *(const float4*)&W[k];
    float4 xv = *(const float4*)&xs[k];
    s += wv.x * xv.x + wv.y * xv.y + wv.z * xv.z + wv.w * xv.w;
  }
  part[o][seg] = s;
  __syncthreads();
  if (tid < 32) {
    float tsum = 0.f;
#pragma unroll
    for (int i = 0; i < 8; ++i) tsum += part[tid][i];
    if (tid < 16) {
      beta[(size_t)bt * NV_ + tid] = 1.f / (1.f + expf(-tsum));
    } else {
      const int h = tid - 16;
      float aa = tsum + dtb[h];
      float sp = (aa > 20.f) ? aa : log1pf(expf(aa));
      gout[(size_t)bt * NV_ + h] = -expf(alog[h]) * sp;
    }
  }
}

// ---------------------------------------------------------------------------
// Depthwise causal conv1d (K=4, left zero-pad) + silu, bf16 in -> fp32 out.
// ---------------------------------------------------------------------------
__global__ __launch_bounds__(256)
void k_conv_silu(const ushort_t* __restrict__ qkv, const float* __restrict__ cw,
                 float* __restrict__ act) {
  const unsigned idx = blockIdx.x * 256u + threadIdx.x;  // B*T*CD/4 total
  const unsigned c4  = idx & (CD_ / 4 - 1);
  const unsigned bt  = idx >> 10;                        // / (CD_/4)
  const int t = bt & (T_ - 1);
  const int c = c4 * 4;
  const ushort_t* rowp = qkv + (size_t)bt * CD_ + c;
  float wf[4][4];
#pragma unroll
  for (int i = 0; i < 4; ++i) {
    float4 w = *(const float4*)&cw[(c + i) * 4];
    wf[i][0] = w.x; wf[i][1] = w.y; wf[i][2] = w.z; wf[i][3] = w.w;
  }
  float a[4] = {0.f, 0.f, 0.f, 0.f};
#pragma unroll
  for (int j = 0; j < 4; ++j) {
    const int tt = t - 3 + j;
    if (tt >= 0) {
      short4v iv = *(const short4v*)(rowp + ((ptrdiff_t)j - 3) * CD_);
#pragma unroll
      for (int i = 0; i < 4; ++i) a[i] += b2f((ushort_t)iv[i]) * wf[i][j];
    }
  }
  float4 o;
  o.x = a[0] / (1.f + expf(-a[0]));
  o.y = a[1] / (1.f + expf(-a[1]));
  o.z = a[2] / (1.f + expf(-a[2]));
  o.w = a[3] / (1.f + expf(-a[3]));
  *(float4*)(act + (size_t)bt * CD_ + c) = o;
}

// ---------------------------------------------------------------------------
// L2-normalize q (with HD^-1/2 scale) and k rows in-place (fp32). Wave per row.
// ---------------------------------------------------------------------------
__global__ __launch_bounds__(256)
void k_l2norm_qk(float* __restrict__ act) {
  const int row  = blockIdx.x * 4 + (threadIdx.x >> 6);  // B*T*16 rows
  const int lane = threadIdx.x & 63;
  const int bt = row >> 4, s = row & 15;
  float* p = act + (size_t)bt * CD_ + (s < 8 ? s * HD_ : KD_ + (s - 8) * HD_);
  float2 v = *(float2*)&p[lane * 2];
  float ss = v.x * v.x + v.y * v.y;
#pragma unroll
  for (int m = 1; m < 64; m <<= 1) ss += __shfl_xor(ss, m);
  float scale = 1.f / fmaxf(sqrtf(ss), 1e-12f);
  if (s < 8) scale *= 0.08838834764831845f;  // HD^-0.5
  v.x *= scale; v.y *= scale;
  *(float2*)&p[lane * 2] = v;
}

// ---------------------------------------------------------------------------
// Chunked gated delta-rule. One WG = (b, v-head h, 32-wide v-slice).
// C=64 timesteps per chunk, 32 chunks sequential. S^T[e][d] fp32 in LDS.
// MFMA frag pattern identical to k_gemm_bt (verified): operands [i][k-contig],
// acc D[(lane>>4)*4+r][lane&15].
// ---------------------------------------------------------------------------
__device__ __forceinline__ bf16x8 cvt8f(const float* p) {
  float4 a = *(const float4*)p;
  float4 b = *(const float4*)(p + 4);
  bf16x8 o;
  o[0] = (__bf16)a.x; o[1] = (__bf16)a.y; o[2] = (__bf16)a.z; o[3] = (__bf16)a.w;
  o[4] = (__bf16)b.x; o[5] = (__bf16)b.y; o[6] = (__bf16)b.z; o[7] = (__bf16)b.w;
  return o;
}

__global__ __launch_bounds__(256)
void k_chunk(const float* __restrict__ act, const float* __restrict__ gB,
             const float* __restrict__ betaB, float* __restrict__ ob) {
  __shared__ alignas(16) __bf16 Kl[64][136];   // 17408 B  K chunk (bf16)
  __shared__ alignas(16) float  S32[32][132];  // 16896 B  S^T[e][d] fp32
  __shared__ alignas(16) __bf16 Ut[32][72];    //  4608 B  U^T[e][t] bf16
  __shared__ alignas(16) char   uni[24896];    // phase-aliased region
  __shared__ float gc[65], Et[65], Rt[65], bts[64];

  __bf16 (*AbL)[40] = (__bf16(*)[40])(uni);            // [64][40]  P1-P3
  __bf16 (*AbH)[33] = (__bf16(*)[33])(uni + 5120);     // [32][33]  P1-P3
  float  (*rhs)[33] = (float (*)[33])(uni + 7232);     // [64][33]  P2-P3
  __bf16 (*Pm)[72]  = (__bf16(*)[72])(uni + 15680);    // [64][72]  P1-P4
  __bf16 (*KT)[72]  = (__bf16(*)[72])(uni);            // [128][72] P4.5-P5

  const int wg = blockIdx.x;                  // 128 = B*NV*(HD/32)
  const int ep = wg & 3, h = (wg >> 2) & 15, b = wg >> 6;
  const int e0 = ep * 32;
  const int tid = threadIdx.x, lane = tid & 63, wave = tid >> 6;
  const int hq = h >> 1;                      // GQA
  const int l15 = lane & 15;
  const int kcol0 = (lane >> 4) * 8;
  const int rrow = (lane >> 4) * 4;

  const float* baseQ = act + (size_t)b * T_ * CD_ + hq * HD_;
  const float* baseK = baseQ + KD_;
  const float* baseV = act + (size_t)b * T_ * CD_ + 2 * KD_ + h * HD_ + e0;
  float* obp = ob + ((size_t)b * T_ * NV_ + h) * HD_ + e0;

  for (int i = tid; i < 32 * 132; i += 256) ((float*)S32)[i] = 0.f;
  __syncthreads();

  for (int c = 0; c < T_ / 64; ++c) {
    const int t0 = c * 64;

    // ---- P0a: log-decay inclusive scan (wave 0), beta load
    if (tid < 64) {
      float g = gB[((size_t)b * T_ + t0 + tid) * NV_ + h];
      bts[tid] = betaB[((size_t)b * T_ + t0 + tid) * NV_ + h];
#pragma unroll
      for (int o = 1; o < 64; o <<= 1) {
        float up = __shfl_up(g, (unsigned)o);
        if (tid >= o) g += up;
      }
      gc[tid + 1] = g;
      if (tid == 0) gc[0] = 0.f;
    }
    __syncthreads();

    // ---- P0b: centered exp tables + stage K chunk to LDS (bf16)
    if (tid < 65) {
      float gm = gc[32];
      Et[tid] = __expf(gc[tid] - gm);
      Rt[tid] = __expf(gm - gc[tid]);
    }
    {
      const int t = tid >> 2, d0 = (tid & 3) * 32;
      const float* src = baseK + (size_t)(t0 + t) * CD_ + d0;
#pragma unroll
      for (int j = 0; j < 8; ++j) {
        float4 v = *(const float4*)(src + j * 4);
        Kl[t][d0 + j * 4 + 0] = (__bf16)v.x;
        Kl[t][d0 + j * 4 + 1] = (__bf16)v.y;
        Kl[t][d0 + j * 4 + 2] = (__bf16)v.z;
        Kl[t][d0 + j * 4 + 3] = (__bf16)v.w;
      }
    }
    __syncthreads();

    // ---- P1: Ab = -beta*decay-scaled KK^T (strict lower); Pm = decay-scaled
    //          QK^T (lower incl diag). Wave w owns t-tile w.
    bf16x8 kf[4], qf[4];
#pragma unroll
    for (int kk = 0; kk < 4; ++kk) {
      kf[kk] = *(const bf16x8*)&Kl[16 * wave + l15][kk * 32 + kcol0];
      const float* qs = baseQ + (size_t)(t0 + 16 * wave + l15) * CD_ + kk * 32 + kcol0;
      qf[kk] = cvt8f(qs);
    }
#pragma unroll
    for (int st = 0; st < 4; ++st) {
      f32x4 accA = {}, accP = {};
#pragma unroll
      for (int kk = 0; kk < 4; ++kk) {
        bf16x8 bfr = *(const bf16x8*)&Kl[st * 16 + l15][kk * 32 + kcol0];
        accA = __builtin_amdgcn_mfma_f32_16x16x32_bf16(kf[kk], bfr, accA, 0, 0, 0);
        accP = __builtin_amdgcn_mfma_f32_16x16x32_bf16(qf[kk], bfr, accP, 0, 0, 0);
      }
      const int scol = st * 16 + l15;
#pragma unroll
      for (int r = 0; r < 4; ++r) {
        const int t = 16 * wave + rrow + r;
        const float sc = Et[t + 1] * Rt[scol + 1];
        if (scol < t) {
          const float av = -bts[t] * sc * accA[r];
          if (scol < 32) AbL[t][scol] = (__bf16)av;
          else           AbH[t - 32][scol - 32] = (__bf16)av;
        }
        Pm[t][scol] = (__bf16)((scol <= t) ? sc * accP[r] : 0.f);
      }
    }
    __syncthreads();

    // ---- P2: KS = K@S^T, QS = Q@S^T (keep QS acc in regs for P4);
    //          rhs[t][e] = beta_t*(v - gamma_t*KS).
    f32x4 qs0 = {}, qs1 = {};
    {
      f32x4 ks0 = {}, ks1 = {};
#pragma unroll
      for (int kk = 0; kk < 4; ++kk) {
        bf16x8 s0 = cvt8f(&S32[l15][kk * 32 + kcol0]);
        bf16x8 s1 = cvt8f(&S32[16 + l15][kk * 32 + kcol0]);
        ks0 = __builtin_amdgcn_mfma_f32_16x16x32_bf16(kf[kk], s0, ks0, 0, 0, 0);
        qs0 = __builtin_amdgcn_mfma_f32_16x16x32_bf16(qf[kk], s0, qs0, 0, 0, 0);
        ks1 = __builtin_amdgcn_mfma_f32_16x16x32_bf16(kf[kk], s1, ks1, 0, 0, 0);
        qs1 = __builtin_amdgcn_mfma_f32_16x16x32_bf16(qf[kk], s1, qs1, 0, 0, 0);
      }
#pragma unroll
      for (int r = 0; r < 4; ++r) {
        const int t = 16 * wave + rrow + r;
        const float gt = Et[t + 1] * Rt[0];
        const float v0 = baseV[(size_t)(t0 + t) * CD_ + l15];
        const float v1 = baseV[(size_t)(t0 + t) * CD_ + 16 + l15];
        rhs[t][l15]      = bts[t] * (v0 - gt * ks0[r]);
        rhs[t][16 + l15] = bts[t] * (v1 - gt * ks1[r]);
      }
    }
    __syncthreads();

    // ---- P3a: forward substitution, block A (t = 0..31), threads = e
    if (tid < 32) {
      const int e = tid;
      float u[32];
#pragma unroll
      for (int j = 0; j < 32; ++j) {
        float a = rhs[j][e];
#pragma unroll
        for (int i = 0; i < j; ++i) a += (float)AbL[j][i] * u[i];
        u[j] = a;
        Ut[e][j] = (__bf16)a;
      }
    }
    __syncthreads();

    // ---- P3b: cross-block correction rhs[32+t'] += Ab[32+t'][0..31] @ U
    {
      const int tt = wave >> 1, et = wave & 1;
      f32x4 acc = {};
      bf16x8 af = *(const bf16x8*)&AbL[32 + 16 * tt + l15][kcol0];
      bf16x8 uf = *(const bf16x8*)&Ut[16 * et + l15][kcol0];
      acc = __builtin_amdgcn_mfma_f32_16x16x32_bf16(af, uf, acc, 0, 0, 0);
#pragma unroll
      for (int r = 0; r < 4; ++r)
        rhs[32 + 16 * tt + rrow + r][16 * et + l15] += acc[r];
    }
    __syncthreads();

    // ---- P3c: forward substitution, block B (t = 32..63)
    if (tid < 32) {
      const int e = tid;
      float u[32];
#pragma unroll
      for (int j = 0; j < 32; ++j) {
        float a = rhs[32 + j][e];
#pragma unroll
        for (int i = 0; i < j; ++i) a += (float)AbH[j][i] * u[i];
        u[j] = a;
        Ut[e][32 + j] = (__bf16)a;
      }
    }
    __syncthreads();

    // ---- P4: O = Pm @ U^T + gamma_t * QS  -> global obuf
    {
      f32x4 o0 = {}, o1 = {};
#pragma unroll
      for (int ks2 = 0; ks2 < 2; ++ks2) {
        bf16x8 pf  = *(const bf16x8*)&Pm[16 * wave + l15][ks2 * 32 + kcol0];
        bf16x8 uu0 = *(const bf16x8*)&Ut[l15][ks2 * 32 + kcol0];
        bf16x8 uu1 = *(const bf16x8*)&Ut[16 + l15][ks2 * 32 + kcol0];
        o0 = __builtin_amdgcn_mfma_f32_16x16x32_bf16(pf, uu0, o0, 0, 0, 0);
        o1 = __builtin_amdgcn_mfma_f32_16x16x32_bf16(pf, uu1, o1, 0, 0, 0);
      }
#pragma unroll
      for (int r = 0; r < 4; ++r) {
        const int t = 16 * wave + rrow + r;
        const float gt = Et[t + 1] * Rt[0];
        obp[(size_t)(t0 + t) * (NV_ * HD_) + l15]      = o0[r] + gt * qs0[r];
        obp[(size_t)(t0 + t) * (NV_ * HD_) + 16 + l15] = o1[r] + gt * qs1[r];
      }
    }
    __syncthreads();   // Pm/Ab/rhs dead; uni region becomes KT

    // ---- P4.5: KT[d][t] = Kl[t][d]
    {
      const int d = tid >> 1, th0 = (tid & 1) * 32;
#pragma unroll
      for (int j = 0; j < 32; ++j) KT[d][th0 + j] = Kl[th0 + j][d];
    }
    __syncthreads();

    // ---- P5: S^T = gamma_C*S^T + (scaled U)^T @ K  via KT
    {
      const int et5 = wave & 1, dtb0 = (wave >> 1) * 4;
      bf16x8 uf[2];
#pragma unroll
      for (int ks2 = 0; ks2 < 2; ++ks2) {
        bf16x8 raw = *(const bf16x8*)&Ut[16 * et5 + l15][ks2 * 32 + kcol0];
        bf16x8 o;
#pragma unroll
        for (int j = 0; j < 8; ++j) {
          const int t = ks2 * 32 + kcol0 + j;
          o[j] = (__bf16)((float)raw[j] * (Et[64] * Rt[t + 1]));
        }
        uf[ks2] = o;
      }
      const float gC = Et[64] * Rt[0];
#pragma unroll
      for (int dt = 0; dt < 4; ++dt) {
        f32x4 acc = {};
#pragma unroll
        for (int ks2 = 0; ks2 < 2; ++ks2) {
          bf16x8 ktf = *(const bf16x8*)&KT[16 * (dtb0 + dt) + l15][ks2 * 32 + kcol0];
          acc = __builtin_amdgcn_mfma_f32_16x16x32_bf16(uf[ks2], ktf, acc, 0, 0, 0);
        }
#pragma unroll
        for (int r = 0; r < 4; ++r) {
          const int e = 16 * et5 + rrow + r;
          const int d = 16 * (dtb0 + dt) + l15;
          S32[e][d] = gC * S32[e][d] + acc[r];
        }
      }
    }
    __syncthreads();
  }
}

// ---------------------------------------------------------------------------
// Gated RMSNorm: out = (o/rms(o)) * norm_w * silu(z); fp32 o, bf16 z,
// fp32 norm_w -> bf16 out (final GEMM operand).
// ---------------------------------------------------------------------------
__global__ __launch_bounds__(256)
void k_gate_rms(const float* __restrict__ ob, const ushort_t* __restrict__ z,
                const float* __restrict__ nw, ushort_t* __restrict__ og) {
  const int row  = blockIdx.x * 4 + (threadIdx.x >> 6);  // B*T*NV rows
  const int lane = threadIdx.x & 63;
  const float* op = ob + (size_t)row * HD_;
  float2 v = *(const float2*)&op[lane * 2];
  float ss = v.x * v.x + v.y * v.y;
#pragma unroll
  for (int m = 1; m < 64; m <<= 1) ss += __shfl_xor(ss, m);
  const float r = 1.f / sqrtf(ss * (1.f / HD_) + 1e-6f);
  unsigned int zz = *(const unsigned int*)&z[(size_t)row * HD_ + lane * 2];
  float z0 = b2f((ushort_t)(zz & 0xffffu));
  float z1 = b2f((ushort_t)(zz >> 16));
  float2 w = *(const float2*)&nw[lane * 2];
  float g0 = z0 / (1.f + expf(-z0));
  float g1 = z1 / (1.f + expf(-z1));
  unsigned int pack = (unsigned int)f2b(v.x * r * w.x * g0)
                    | ((unsigned int)f2b(v.y * r * w.y * g1) << 16);
  *(unsigned int*)&og[(size_t)row * HD_ + lane * 2] = pack;
}

// ---------------------------------------------------------------------------
extern "C" void kernel_launch(void* const* d_in, const int* in_sizes, int n_in,
                              void* d_out, int out_size, void* d_ws, size_t ws_size,
                              hipStream_t stream) {
  const float* x    = (const float*)d_in[0];
  const float* Wqkv = (const float*)d_in[1];
  const float* Wz   = (const float*)d_in[2];
  const float* Wb   = (const float*)d_in[3];
  const float* Wa   = (const float*)d_in[4];
  const float* cw   = (const float*)d_in[5];
  const float* dtb  = (const float*)d_in[6];
  const float* alog = (const float*)d_in[7];
  const float* nw   = (const float*)d_in[8];
  const float* Wout = (const float*)d_in[9];

  char* p = (char*)d_ws;
  ushort_t* qkv_raw = (ushort_t*)p; p += (size_t)B_ * T_ * CD_ * 2;       // 33.5 MB
  ushort_t* zbuf    = (ushort_t*)p; p += (size_t)B_ * T_ * VD_ * 2;       // 16.8 MB
  char*     actBase = p;
  float*    act     = (float*)p;    p += (size_t)B_ * T_ * CD_ * 4;       // 67.1 MB
  float*    betaB   = (float*)p;    p += (size_t)B_ * T_ * NV_ * 4;
  float*    gBuf    = (float*)p;    p += (size_t)B_ * T_ * NV_ * 4;
  float*    obuf    = (float*)p;    p += (size_t)B_ * T_ * NV_ * HD_ * 4; // 33.5 MB
  ushort_t* WoutB   = (ushort_t*)p; p += (size_t)HID_ * VD_ * 2;          // 8.4 MB
  // bf16 cast buffers aliased into act region (dead before conv writes act):
  ushort_t* xB    = (ushort_t*)(actBase);                                 // 16.8 MB
  ushort_t* WqkvB = (ushort_t*)(actBase + (size_t)B_ * T_ * HID_ * 2);    // 16.8 MB
  ushort_t* WzB   = (ushort_t*)(actBase + (size_t)B_ * T_ * HID_ * 2
                                        + (size_t)CD_ * HID_ * 2);        // 8.4 MB
  ushort_t* outg  = qkv_raw;        // reuse: qkv_raw dead after conv

  const int M = B_ * T_;  // 4096

  hipLaunchKernelGGL(k_cast_bf16, dim3(M * HID_ / 4 / 256), dim3(256), 0, stream,
                     x, xB, M * HID_ / 4);
  hipLaunchKernelGGL(k_cast_bf16, dim3(CD_ * HID_ / 4 / 256), dim3(256), 0, stream,
                     Wqkv, WqkvB, CD_ * HID_ / 4);
  hipLaunchKernelGGL(k_cast_bf16, dim3(VD_ * HID_ / 4 / 256), dim3(256), 0, stream,
                     Wz, WzB, VD_ * HID_ / 4);
  hipLaunchKernelGGL(k_cast_bf16, dim3(HID_ * VD_ / 4 / 256), dim3(256), 0, stream,
                     Wout, WoutB, HID_ * VD_ / 4);

  hipLaunchKernelGGL(k_gemm_bt<ushort_t>, dim3(CD_ / 128, M / 128), dim3(256), 0, stream,
                     xB, WqkvB, qkv_raw, M, CD_, HID_);
  hipLaunchKernelGGL(k_gemm_bt<ushort_t>, dim3(VD_ / 128, M / 128), dim3(256), 0, stream,
                     xB, WzB, zbuf, M, VD_, HID_);
  hipLaunchKernelGGL(k_proj_ba, dim3(M), dim3(256), 0, stream,
                     x, Wb, Wa, dtb, alog, betaB, gBuf);
  hipLaunchKernelGGL(k_conv_silu, dim3(M * CD_ / 4 / 256), dim3(256), 0, stream,
                     qkv_raw, cw, act);
  hipLaunchKernelGGL(k_l2norm_qk, dim3(M * 16 / 4), dim3(256), 0, stream, act);
  hipLaunchKernelGGL(k_chunk, dim3(B_ * NV_ * (HD_ / 32)), dim3(256), 0, stream,
                     act, gBuf, betaB, obuf);
  hipLaunchKernelGGL(k_gate_rms, dim3(M * NV_ / 4), dim3(256), 0, stream,
                     obuf, zbuf, nw, outg);
  hipLaunchKernelGGL(k_gemm_bt<float>, dim3(HID_ / 128, M / 128), dim3(256), 0, stream,
                     outg, WoutB, (float*)d_out, M, HID_, VD_);
}

// Round 6
// 677.947 us; speedup vs baseline: 2.3649x; 1.2392x over previous
//
#include <hip/hip_runtime.h>
#include <cstdint>
#include <cstddef>

// GatedDeltaNet forward, MI355X/gfx950.
// Inputs/outputs are fp32 (reference computes in jnp.float32).
// Pipeline: cast(x,Wqkv,Wz,Wout -> bf16) -> [gemm qkv] [gemm z] [proj b/a (g)]
//           -> conv1d+silu (fp32) -> l2norm q,k
//           -> k_prep (PARALLEL per chunk: tables, KK^T/QK^T, T-solve -> -Wk, Uloc, Pm, K^T)
//           -> k_scan (SEQUENTIAL 32 chunks, 32 WGs: u = Uloc - Wk S; o = g*QS + Pm u;
//                      S <- gC*S + K^T (esc*u))   [all MFMA, state fp32 in regs]
//           -> gated RMSNorm*silu(z) (bf16) -> [gemm out -> fp32 d_out].
// R5->R6: monolithic k_chunk (440us, latency-bound: 128 WGs, 30k cy/chunk) split
// into parallel k_prep (1024 WGs) + minimal sequential k_scan (112 MFMA/wave/chunk).

typedef unsigned short ushort_t;
typedef __attribute__((ext_vector_type(8))) __bf16 bf16x8;
typedef __attribute__((ext_vector_type(4))) float f32x4;
typedef __attribute__((ext_vector_type(4))) short short4v;

#define B_   2
#define T_   2048
#define HID_ 2048
#define NK_  8
#define NV_  16
#define HD_  128
#define KD_  1024
#define VD_  2048
#define CD_  4096

__device__ __forceinline__ float b2f(ushort_t u) {
  union { unsigned int i; float f; } v; v.i = ((unsigned int)u) << 16; return v.f;
}
__device__ __forceinline__ ushort_t f2b(float f) {   // RNE bf16 round
  unsigned int x = __builtin_bit_cast(unsigned int, f);
  unsigned int r = x + 0x7fffu + ((x >> 16) & 1u);
  return (ushort_t)(r >> 16);
}

// ---------------------------------------------------------------------------
// fp32 -> bf16 cast (vectorized: 4 elems/thread)
// ---------------------------------------------------------------------------
__global__ __launch_bounds__(256)
void k_cast_bf16(const float* __restrict__ in, ushort_t* __restrict__ out, int n4) {
  const int i = blockIdx.x * 256 + threadIdx.x;
  if (i >= n4) return;
  float4 v = *(const float4*)(in + (size_t)i * 4);
  short4v o;
  o[0] = (short)f2b(v.x); o[1] = (short)f2b(v.y);
  o[2] = (short)f2b(v.z); o[3] = (short)f2b(v.w);
  *(short4v*)(out + (size_t)i * 4) = o;
}

// ---------------------------------------------------------------------------
// GEMM: C[m,n] = sum_k A[m,k] * B[n,k]   (A: MxK row-major bf16, B: NxK bf16)
// m97 structure: 128x128 tile, BK=32, 4 waves, global_load_lds width 16.
// ---------------------------------------------------------------------------
template <typename OutT>
__global__ __launch_bounds__(256)
void k_gemm_bt(const ushort_t* __restrict__ A, const ushort_t* __restrict__ Bw,
               OutT* __restrict__ C, int M, int N, int K) {
  __shared__ alignas(16) ushort_t As[128 * 32];
  __shared__ alignas(16) ushort_t Bs[128 * 32];
  const int tid  = threadIdx.x;
  const int lane = tid & 63;
  const int wave = tid >> 6;
  const int wr = wave >> 1, wc = wave & 1;
  const size_t row0 = (size_t)blockIdx.y * 128;
  const size_t col0 = (size_t)blockIdx.x * 128;

  f32x4 acc[4][4] = {};
  const int fr = lane & 15;            // fragment row/col
  const int ks = (lane >> 4) * 8;      // k-slice within BK=32

  for (int kt = 0; kt < K; kt += 32) {
    __syncthreads();                   // LDS reads of prev tile done
#pragma unroll
    for (int ch = 0; ch < 2; ++ch) {
      const int li  = ch * 256 + tid;  // 16B-unit index, 512 per 8KB tile
      const int row = li >> 2;
      const int cp  = li & 3;
      const ushort_t* ga = A  + (row0 + row) * (size_t)K + kt + cp * 8;
      const ushort_t* gb = Bw + (col0 + row) * (size_t)K + kt + cp * 8;
      ushort_t* la = As + ((li >> 6) << 9);  // wave-uniform 1KB chunk base
      ushort_t* lb = Bs + ((li >> 6) << 9);
      __builtin_amdgcn_global_load_lds(
          (const __attribute__((address_space(1))) unsigned int*)ga,
          (__attribute__((address_space(3))) unsigned int*)la, 16, 0, 0);
      __builtin_amdgcn_global_load_lds(
          (const __attribute__((address_space(1))) unsigned int*)gb,
          (__attribute__((address_space(3))) unsigned int*)lb, 16, 0, 0);
    }
    __syncthreads();                   // vmcnt(0) drained by compiler

    bf16x8 af[4], bfv[4];
#pragma unroll
    for (int m = 0; m < 4; ++m)
      af[m]  = *(const bf16x8*)&As[(wr * 64 + m * 16 + fr) * 32 + ks];
#pragma unroll
    for (int n = 0; n < 4; ++n)
      bfv[n] = *(const bf16x8*)&Bs[(wc * 64 + n * 16 + fr) * 32 + ks];
#pragma unroll
    for (int m = 0; m < 4; ++m)
#pragma unroll
      for (int n = 0; n < 4; ++n)
        acc[m][n] = __builtin_amdgcn_mfma_f32_16x16x32_bf16(af[m], bfv[n], acc[m][n], 0, 0, 0);
  }

  const int r4 = (lane >> 4) * 4;      // C/D: col=lane&15, row=(lane>>4)*4+reg
#pragma unroll
  for (int m = 0; m < 4; ++m)
#pragma unroll
    for (int n = 0; n < 4; ++n)
#pragma unroll
      for (int j = 0; j < 4; ++j) {
        const size_t row = row0 + wr * 64 + m * 16 + r4 + j;
        const size_t col = col0 + wc * 64 + n * 16 + fr;
        if constexpr (sizeof(OutT) == 4)
          C[row * (size_t)N + col] = acc[m][n][j];
        else
          C[row * (size_t)N + col] = (OutT)f2b(acc[m][n][j]);
      }
}

// ---------------------------------------------------------------------------
// b/a projection + activation (fp32 in): beta = sigmoid(x@Wb^T),
// g = -exp(A_log) * softplus(x@Wa^T + dt_bias)   [log-decay, for chunk cumsum]
// ---------------------------------------------------------------------------
__global__ __launch_bounds__(256)
void k_proj_ba(const float* __restrict__ x, const float* __restrict__ Wb,
               const float* __restrict__ Wa, const float* __restrict__ dtb,
               const float* __restrict__ alog,
               float* __restrict__ beta, float* __restrict__ gout) {
  __shared__ float xs[HID_];
  __shared__ float part[32][8];
  const int bt = blockIdx.x, tid = threadIdx.x;
  const float* xr = x + (size_t)bt * HID_;
  *(float4*)&xs[tid * 8]     = *(const float4*)&xr[tid * 8];
  *(float4*)&xs[tid * 8 + 4] = *(const float4*)&xr[tid * 8 + 4];
  __syncthreads();
  const int o = tid >> 3, seg = tid & 7;
  const float* W = (o < 16) ? (Wb + (size_t)o * HID_) : (Wa + (size_t)(o - 16) * HID_);
  float s = 0.f;
  for (int k = seg * 256; k < seg * 256 + 256; k += 4) {
    float4 wv = *(const float4*)&W[k];
    float4 xv = *(const float4*)&xs[k];
    s += wv.x * xv.x + wv.y * xv.y + wv.z * xv.z + wv.w * xv.w;
  }
  part[o][seg] = s;
  __syncthreads();
  if (tid < 32) {
    float tsum = 0.f;
#pragma unroll
    for (int i = 0; i < 8; ++i) tsum += part[tid][i];
    if (tid < 16) {
      beta[(size_t)bt * NV_ + tid] = 1.f / (1.f + expf(-tsum));
    } else {
      const int h = tid - 16;
      float aa = tsum + dtb[h];
      float sp = (aa > 20.f) ? aa : log1pf(expf(aa));
      gout[(size_t)bt * NV_ + h] = -expf(alog[h]) * sp;
    }
  }
}

// ---------------------------------------------------------------------------
// Depthwise causal conv1d (K=4, left zero-pad) + silu, bf16 in -> fp32 out.
// ---------------------------------------------------------------------------
__global__ __launch_bounds__(256)
void k_conv_silu(const ushort_t* __restrict__ qkv, const float* __restrict__ cw,
                 float* __restrict__ act) {
  const unsigned idx = blockIdx.x * 256u + threadIdx.x;  // B*T*CD/4 total
  const unsigned c4  = idx & (CD_ / 4 - 1);
  const unsigned bt  = idx >> 10;                        // / (CD_/4)
  const int t = bt & (T_ - 1);
  const int c = c4 * 4;
  const ushort_t* rowp = qkv + (size_t)bt * CD_ + c;
  float wf[4][4];
#pragma unroll
  for (int i = 0; i < 4; ++i) {
    float4 w = *(const float4*)&cw[(c + i) * 4];
    wf[i][0] = w.x; wf[i][1] = w.y; wf[i][2] = w.z; wf[i][3] = w.w;
  }
  float a[4] = {0.f, 0.f, 0.f, 0.f};
#pragma unroll
  for (int j = 0; j < 4; ++j) {
    const int tt = t - 3 + j;
    if (tt >= 0) {
      short4v iv = *(const short4v*)(rowp + ((ptrdiff_t)j - 3) * CD_);
#pragma unroll
      for (int i = 0; i < 4; ++i) a[i] += b2f((ushort_t)iv[i]) * wf[i][j];
    }
  }
  float4 o;
  o.x = a[0] / (1.f + expf(-a[0]));
  o.y = a[1] / (1.f + expf(-a[1]));
  o.z = a[2] / (1.f + expf(-a[2]));
  o.w = a[3] / (1.f + expf(-a[3]));
  *(float4*)(act + (size_t)bt * CD_ + c) = o;
}

// ---------------------------------------------------------------------------
// L2-normalize q (with HD^-1/2 scale) and k rows in-place (fp32). Wave per row.
// ---------------------------------------------------------------------------
__global__ __launch_bounds__(256)
void k_l2norm_qk(float* __restrict__ act) {
  const int row  = blockIdx.x * 4 + (threadIdx.x >> 6);  // B*T*16 rows
  const int lane = threadIdx.x & 63;
  const int bt = row >> 4, s = row & 15;
  float* p = act + (size_t)bt * CD_ + (s < 8 ? s * HD_ : KD_ + (s - 8) * HD_);
  float2 v = *(float2*)&p[lane * 2];
  float ss = v.x * v.x + v.y * v.y;
#pragma unroll
  for (int m = 1; m < 64; m <<= 1) ss += __shfl_xor(ss, m);
  float scale = 1.f / fmaxf(sqrtf(ss), 1e-12f);
  if (s < 8) scale *= 0.08838834764831845f;  // HD^-0.5
  v.x *= scale; v.y *= scale;
  *(float2*)&p[lane * 2] = v;
}

// ---------------------------------------------------------------------------
__device__ __forceinline__ bf16x8 cvt8f(const float* p) {
  float4 a = *(const float4*)p;
  float4 b = *(const float4*)(p + 4);
  bf16x8 o;
  o[0] = (__bf16)a.x; o[1] = (__bf16)a.y; o[2] = (__bf16)a.z; o[3] = (__bf16)a.w;
  o[4] = (__bf16)b.x; o[5] = (__bf16)b.y; o[6] = (__bf16)b.z; o[7] = (__bf16)b.w;
  return o;
}

// ---------------------------------------------------------------------------
// k_prep: per-chunk parallel precompute. grid = B*NV*NC = 1024.
// Outputs (bf16, padded strides for conflict-free pass-2 frag reads):
//   WkG[bhc][64][136] = -T(beta*Gamma*K)   (negated!)
//   UlG[bhc][64][136] =  T(beta*V)
//   PmG[bhc][64][72]  =  masked decay-scaled QK^T
//   kTG[b][hq][c][128][72] = K^T (raw k, bf16)       [h even writes]
//   gtG[bhc][64]      =  inclusive cumsum of log-decay
// ---------------------------------------------------------------------------
__global__ __launch_bounds__(256, 1)
void k_prep(const float* __restrict__ act, const float* __restrict__ gB,
            const float* __restrict__ betaB,
            ushort_t* __restrict__ WkG, ushort_t* __restrict__ UlG,
            ushort_t* __restrict__ PmG, ushort_t* __restrict__ kTG,
            float* __restrict__ gtG) {
  __shared__ __bf16 Kl[64][136];
  __shared__ __bf16 AbL[64][40];
  __shared__ __bf16 AbH[32][33];
  __shared__ __bf16 Xl[64][256];
  __shared__ float gc[65], Et[65], Rt[65], bts[64], geT[64];

  const int wg = blockIdx.x;                 // ((b*16+h)*32 + c)
  const int c = wg & 31, h = (wg >> 5) & 15, b = wg >> 9;
  const int hq = h >> 1, t0 = c * 64;
  const int tid = threadIdx.x, lane = tid & 63, wave = tid >> 6;
  const int l15 = lane & 15, kcol0 = (lane >> 4) * 8, rrow = (lane >> 4) * 4;
  const size_t bhc = (size_t)wg;

  const float* baseQ = act + (size_t)b * T_ * CD_ + hq * HD_;
  const float* baseK = baseQ + KD_;

  // P0a: log-decay scan + beta
  if (tid < 64) {
    float g = gB[((size_t)b * T_ + t0 + tid) * NV_ + h];
    bts[tid] = betaB[((size_t)b * T_ + t0 + tid) * NV_ + h];
#pragma unroll
    for (int o = 1; o < 64; o <<= 1) {
      float up = __shfl_up(g, (unsigned)o);
      if (tid >= o) g += up;
    }
    gc[tid + 1] = g;
    if (tid == 0) gc[0] = 0.f;
  }
  __syncthreads();
  // P0b: tables + stage K chunk (bf16)
  if (tid < 65) {
    float gm = gc[32];
    Et[tid] = __expf(gc[tid] - gm);
    Rt[tid] = __expf(gm - gc[tid]);
  }
  if (tid < 64) {
    geT[tid] = bts[tid] * __expf(gc[tid + 1]);
    gtG[bhc * 64 + tid] = gc[tid + 1];
  }
  {
    const int t = tid >> 2, d0 = (tid & 3) * 32;
    const float* src = baseK + (size_t)(t0 + t) * CD_ + d0;
#pragma unroll
    for (int j = 0; j < 8; ++j) {
      float4 v = *(const float4*)(src + j * 4);
      Kl[t][d0 + j * 4 + 0] = (__bf16)v.x;
      Kl[t][d0 + j * 4 + 1] = (__bf16)v.y;
      Kl[t][d0 + j * 4 + 2] = (__bf16)v.z;
      Kl[t][d0 + j * 4 + 3] = (__bf16)v.w;
    }
  }
  __syncthreads();

  // P1: Ab (strict lower, -beta*scale*KK^T) in LDS; Pm (masked scale*QK^T) -> global
  {
    bf16x8 kf[4], qf[4];
#pragma unroll
    for (int kk = 0; kk < 4; ++kk) {
      kf[kk] = *(const bf16x8*)&Kl[16 * wave + l15][kk * 32 + kcol0];
      qf[kk] = cvt8f(baseQ + (size_t)(t0 + 16 * wave + l15) * CD_ + kk * 32 + kcol0);
    }
#pragma unroll
    for (int st = 0; st < 4; ++st) {
      f32x4 accA = {}, accP = {};
#pragma unroll
      for (int kk = 0; kk < 4; ++kk) {
        bf16x8 bfr = *(const bf16x8*)&Kl[st * 16 + l15][kk * 32 + kcol0];
        accA = __builtin_amdgcn_mfma_f32_16x16x32_bf16(kf[kk], bfr, accA, 0, 0, 0);
        accP = __builtin_amdgcn_mfma_f32_16x16x32_bf16(qf[kk], bfr, accP, 0, 0, 0);
      }
      const int scol = st * 16 + l15;
#pragma unroll
      for (int r = 0; r < 4; ++r) {
        const int t = 16 * wave + rrow + r;
        const float sc = Et[t + 1] * Rt[scol + 1];
        if (scol < t) {
          const float av = -bts[t] * sc * accA[r];
          if (scol < 32) AbL[t][scol] = (__bf16)av;
          else           AbH[t - 32][scol - 32] = (__bf16)av;
        }
        PmG[bhc * 4608 + (size_t)t * 72 + scol] =
            (scol <= t) ? f2b(sc * accP[r]) : (ushort_t)0;
      }
    }
  }
  // K^T store (h even only; shared by v-head pair)
  if ((h & 1) == 0) {
    const size_t kto = (((size_t)b * 8 + hq) * 32 + c) * (128 * 72);
    const int d = tid >> 1, t8 = (tid & 1) * 32;
#pragma unroll
    for (int i8 = 0; i8 < 4; ++i8) {
      bf16x8 tmp;
#pragma unroll
      for (int jj = 0; jj < 8; ++jj) tmp[jj] = Kl[t8 + i8 * 8 + jj][d];
      *(bf16x8*)(void*)(kTG + kto + (size_t)d * 72 + t8 + i8 * 8) = tmp;
    }
  }
  __syncthreads();

  // P2: triangular solve (I+L)X = RHS, 256 threads = 256 columns
  {
    float r1[32], r2[32];
    if (tid < 128) {
      const int d = tid;
#pragma unroll
      for (int t = 0; t < 32; ++t) r1[t] = geT[t] * (float)Kl[t][d];
#pragma unroll
      for (int t = 0; t < 32; ++t) r2[t] = geT[32 + t] * (float)Kl[32 + t][d];
    } else {
      const int j = tid - 128;
      const float* vsrc = act + ((size_t)b * T_ + t0) * CD_ + 2 * KD_ + h * HD_ + j;
#pragma unroll
      for (int t = 0; t < 32; ++t) r1[t] = bts[t] * vsrc[(size_t)t * CD_];
#pragma unroll
      for (int t = 0; t < 32; ++t) r2[t] = bts[32 + t] * vsrc[(size_t)(32 + t) * CD_];
    }
    float u1[32];
#pragma unroll
    for (int j = 0; j < 32; ++j) {
      float a = r1[j];
#pragma unroll
      for (int i = 0; i < j; ++i) a += (float)AbL[j][i] * u1[i];
      u1[j] = a;
      Xl[j][tid] = (__bf16)a;
    }
#pragma unroll
    for (int t2 = 0; t2 < 32; ++t2) {
      float a = r2[t2];
#pragma unroll
      for (int i = 0; i < 32; ++i) a += (float)AbL[32 + t2][i] * u1[i];
      r2[t2] = a;
    }
    float u2[32];
#pragma unroll
    for (int j = 0; j < 32; ++j) {
      float a = r2[j];
#pragma unroll
      for (int i = 0; i < j; ++i) a += (float)AbH[j][i] * u2[i];
      u2[j] = a;
      Xl[32 + j][tid] = (__bf16)a;
    }
  }
  __syncthreads();

  // P3: copy Xl -> WkG (negated) / UlG, 16B chunks
#pragma unroll
  for (int kck = 0; kck < 4; ++kck) {
    const int q = tid + kck * 256;             // 0..1023
    const int t = q >> 4, d0 = (q & 15) * 8;
    uint4 v = *(const uint4*)&Xl[t][d0];
    v.x ^= 0x80008000u; v.y ^= 0x80008000u; v.z ^= 0x80008000u; v.w ^= 0x80008000u;
    *(uint4*)(void*)(WkG + bhc * (64 * 136) + (size_t)t * 136 + d0) = v;
    uint4 w = *(const uint4*)&Xl[t][128 + d0];
    *(uint4*)(void*)(UlG + bhc * (64 * 136) + (size_t)t * 136 + d0) = w;
  }
}

// ---------------------------------------------------------------------------
// k_scan: sequential inter-chunk state recurrence + fused output. grid = B*NV.
// State S^T[j][d] fp32 in registers (64/lane), bf16 mirror in LDS per chunk.
// ---------------------------------------------------------------------------
__global__ __launch_bounds__(256, 1)
void k_scan(const float* __restrict__ act,
            const ushort_t* __restrict__ WkG, const ushort_t* __restrict__ UlG,
            const ushort_t* __restrict__ PmG, const ushort_t* __restrict__ kTG,
            const float* __restrict__ gtG, float* __restrict__ ob) {
  __shared__ __bf16 S16[128][136];   // 34816 B
  __shared__ __bf16 uTl[128][72];    // 18432 B
  __shared__ float gam[64], esc[64];

  const int wg = blockIdx.x;                 // b*16 + h
  const int h = wg & 15, b = wg >> 4, hq = h >> 1;
  const int tid = threadIdx.x, lane = tid & 63, wave = tid >> 6;
  const int l15 = lane & 15, kcol0 = (lane >> 4) * 8, rrow = (lane >> 4) * 4;

  f32x4 s_acc[2][8] = {};    // j-tiles {2w,2w+1} x 8 d-tiles

  for (int c = 0; c < 32; ++c) {
    const size_t bhc = (size_t)wg * 32 + c;
    const int t0g = c * 64;
    const ushort_t* WkR = WkG + bhc * (64 * 136);
    const ushort_t* UlR = UlG + bhc * (64 * 136);
    const ushort_t* PmR = PmG + bhc * 4608;
    const ushort_t* kTR = kTG + (((size_t)b * 8 + hq) * 32 + c) * (128 * 72);

    const float gCv = gtG[bhc * 64 + 63];
    if (tid < 64) {
      const float gv = gtG[bhc * 64 + tid];
      gam[tid] = __expf(gv);
      esc[tid] = __expf(gCv - gv);
    }
    // S16 <- bf16(S)
#pragma unroll
    for (int jt2 = 0; jt2 < 2; ++jt2)
#pragma unroll
      for (int dt = 0; dt < 8; ++dt)
#pragma unroll
        for (int r = 0; r < 4; ++r)
          S16[(2 * wave + jt2) * 16 + rrow + r][dt * 16 + l15] = (__bf16)s_acc[jt2][dt][r];
    __syncthreads();

    // u-phase: u = Uloc + (-Wk)@S   (acc += after init 0; Uloc added at write)
    bf16x8 wa[4];
#pragma unroll
    for (int kk = 0; kk < 4; ++kk)
      wa[kk] = *(const bf16x8*)(const void*)(WkR + (size_t)(16 * wave + l15) * 136 + kk * 32 + kcol0);
    float uv[8][4];
#pragma unroll
    for (int jt = 0; jt < 8; ++jt)
#pragma unroll
      for (int r = 0; r < 4; ++r)
        uv[jt][r] = b2f(UlR[(size_t)(16 * wave + rrow + r) * 136 + jt * 16 + l15]);
    f32x4 au[8] = {};
#pragma unroll
    for (int kk = 0; kk < 4; ++kk)
#pragma unroll
      for (int jt = 0; jt < 8; ++jt) {
        bf16x8 sb = *(const bf16x8*)&S16[jt * 16 + l15][kk * 32 + kcol0];
        au[jt] = __builtin_amdgcn_mfma_f32_16x16x32_bf16(wa[kk], sb, au[jt], 0, 0, 0);
      }
#pragma unroll
    for (int jt = 0; jt < 8; ++jt)
#pragma unroll
      for (int r = 0; r < 4; ++r)
        uTl[jt * 16 + l15][16 * wave + rrow + r] = (__bf16)(au[jt][r] + uv[jt][r]);
    __syncthreads();

    // QS + o2 = Pm@u; o = gam*QS + o2 -> obuf
    f32x4 qs[8] = {}, o2[8] = {};
#pragma unroll
    for (int kk = 0; kk < 4; ++kk) {
      bf16x8 qa = cvt8f(act + ((size_t)b * T_ + t0g + 16 * wave + l15) * CD_ + hq * HD_ + kk * 32 + kcol0);
#pragma unroll
      for (int jt = 0; jt < 8; ++jt) {
        bf16x8 sb = *(const bf16x8*)&S16[jt * 16 + l15][kk * 32 + kcol0];
        qs[jt] = __builtin_amdgcn_mfma_f32_16x16x32_bf16(qa, sb, qs[jt], 0, 0, 0);
      }
    }
#pragma unroll
    for (int ks = 0; ks < 2; ++ks) {
      bf16x8 pa = *(const bf16x8*)(const void*)(PmR + (size_t)(16 * wave + l15) * 72 + ks * 32 + kcol0);
#pragma unroll
      for (int jt = 0; jt < 8; ++jt) {
        bf16x8 ub = *(const bf16x8*)&uTl[jt * 16 + l15][ks * 32 + kcol0];
        o2[jt] = __builtin_amdgcn_mfma_f32_16x16x32_bf16(pa, ub, o2[jt], 0, 0, 0);
      }
    }
#pragma unroll
    for (int jt = 0; jt < 8; ++jt)
#pragma unroll
      for (int r = 0; r < 4; ++r) {
        const int t = 16 * wave + rrow + r;
        ob[(((size_t)b * T_ + t0g + t) * NV_ + h) * HD_ + jt * 16 + l15] =
            gam[t] * qs[jt][r] + o2[jt][r];
      }

    // S-update: S = gam[63]*S + K^T (esc*u)
    const float gCe = gam[63];
#pragma unroll
    for (int jt2 = 0; jt2 < 2; ++jt2)
#pragma unroll
      for (int dt = 0; dt < 8; ++dt)
#pragma unroll
        for (int r = 0; r < 4; ++r) s_acc[jt2][dt][r] *= gCe;
#pragma unroll
    for (int ks = 0; ks < 2; ++ks) {
      bf16x8 ua[2];
#pragma unroll
      for (int jt2 = 0; jt2 < 2; ++jt2) {
        bf16x8 raw = *(const bf16x8*)&uTl[(2 * wave + jt2) * 16 + l15][ks * 32 + kcol0];
#pragma unroll
        for (int e = 0; e < 8; ++e)
          ua[jt2][e] = (__bf16)((float)raw[e] * esc[ks * 32 + kcol0 + e]);
      }
#pragma unroll
      for (int dt = 0; dt < 8; ++dt) {
        bf16x8 kb = *(const bf16x8*)(const void*)(kTR + (size_t)(dt * 16 + l15) * 72 + ks * 32 + kcol0);
        s_acc[0][dt] = __builtin_amdgcn_mfma_f32_16x16x32_bf16(ua[0], kb, s_acc[0][dt], 0, 0, 0);
        s_acc[1][dt] = __builtin_amdgcn_mfma_f32_16x16x32_bf16(ua[1], kb, s_acc[1][dt], 0, 0, 0);
      }
    }
    __syncthreads();
  }
}

// ---------------------------------------------------------------------------
// Gated RMSNorm: out = (o/rms(o)) * norm_w * silu(z); fp32 o, bf16 z,
// fp32 norm_w -> bf16 out (final GEMM operand).
// ---------------------------------------------------------------------------
__global__ __launch_bounds__(256)
void k_gate_rms(const float* __restrict__ ob, const ushort_t* __restrict__ z,
                const float* __restrict__ nw, ushort_t* __restrict__ og) {
  const int row  = blockIdx.x * 4 + (threadIdx.x >> 6);  // B*T*NV rows
  const int lane = threadIdx.x & 63;
  const float* op = ob + (size_t)row * HD_;
  float2 v = *(const float2*)&op[lane * 2];
  float ss = v.x * v.x + v.y * v.y;
#pragma unroll
  for (int m = 1; m < 64; m <<= 1) ss += __shfl_xor(ss, m);
  const float r = 1.f / sqrtf(ss * (1.f / HD_) + 1e-6f);
  unsigned int zz = *(const unsigned int*)&z[(size_t)row * HD_ + lane * 2];
  float z0 = b2f((ushort_t)(zz & 0xffffu));
  float z1 = b2f((ushort_t)(zz >> 16));
  float2 w = *(const float2*)&nw[lane * 2];
  float g0 = z0 / (1.f + expf(-z0));
  float g1 = z1 / (1.f + expf(-z1));
  unsigned int pack = (unsigned int)f2b(v.x * r * w.x * g0)
                    | ((unsigned int)f2b(v.y * r * w.y * g1) << 16);
  *(unsigned int*)&og[(size_t)row * HD_ + lane * 2] = pack;
}

// ---------------------------------------------------------------------------
extern "C" void kernel_launch(void* const* d_in, const int* in_sizes, int n_in,
                              void* d_out, int out_size, void* d_ws, size_t ws_size,
                              hipStream_t stream) {
  const float* x    = (const float*)d_in[0];
  const float* Wqkv = (const float*)d_in[1];
  const float* Wz   = (const float*)d_in[2];
  const float* Wb   = (const float*)d_in[3];
  const float* Wa   = (const float*)d_in[4];
  const float* cw   = (const float*)d_in[5];
  const float* dtb  = (const float*)d_in[6];
  const float* alog = (const float*)d_in[7];
  const float* nw   = (const float*)d_in[8];
  const float* Wout = (const float*)d_in[9];

  char* p = (char*)d_ws;
  ushort_t* qkv_raw = (ushort_t*)p; p += (size_t)B_ * T_ * CD_ * 2;       // 33.5 MB
  ushort_t* zbuf    = (ushort_t*)p; p += (size_t)B_ * T_ * VD_ * 2;       // 16.8 MB
  char*     actBase = p;
  float*    act     = (float*)p;    p += (size_t)B_ * T_ * CD_ * 4;       // 67.1 MB
  float*    betaB   = (float*)p;    p += (size_t)B_ * T_ * NV_ * 4;
  float*    gBuf    = (float*)p;    p += (size_t)B_ * T_ * NV_ * 4;
  float*    obuf    = (float*)p;    p += (size_t)B_ * T_ * NV_ * HD_ * 4; // 33.5 MB
  ushort_t* WoutB   = (ushort_t*)p; p += (size_t)HID_ * VD_ * 2;          // 8.4 MB
  ushort_t* UlG     = (ushort_t*)p; p += (size_t)1024 * 64 * 136 * 2;     // 17.8 MB
  ushort_t* PmG     = (ushort_t*)p; p += (size_t)1024 * 64 * 72 * 2;      //  9.4 MB
  // overlays in qkv_raw region (dead after conv; outg written after k_scan):
  ushort_t* WkG = qkv_raw;                                                // 17.8 MB
  ushort_t* kTG = (ushort_t*)((char*)qkv_raw + 17825792);                 //  9.4 MB
  float*    gtG = (float*)((char*)qkv_raw + 27262976);                    //  0.26 MB
  // bf16 cast buffers aliased into act region (dead before conv writes act):
  ushort_t* xB    = (ushort_t*)(actBase);                                 // 16.8 MB
  ushort_t* WqkvB = (ushort_t*)(actBase + (size_t)B_ * T_ * HID_ * 2);    // 16.8 MB
  ushort_t* WzB   = (ushort_t*)(actBase + (size_t)B_ * T_ * HID_ * 2
                                        + (size_t)CD_ * HID_ * 2);        // 8.4 MB
  ushort_t* outg  = qkv_raw;        // reuse again after k_scan

  const int M = B_ * T_;  // 4096

  hipLaunchKernelGGL(k_cast_bf16, dim3(M * HID_ / 4 / 256), dim3(256), 0, stream,
                     x, xB, M * HID_ / 4);
  hipLaunchKernelGGL(k_cast_bf16, dim3(CD_ * HID_ / 4 / 256), dim3(256), 0, stream,
                     Wqkv, WqkvB, CD_ * HID_ / 4);
  hipLaunchKernelGGL(k_cast_bf16, dim3(VD_ * HID_ / 4 / 256), dim3(256), 0, stream,
                     Wz, WzB, VD_ * HID_ / 4);
  hipLaunchKernelGGL(k_cast_bf16, dim3(HID_ * VD_ / 4 / 256), dim3(256), 0, stream,
                     Wout, WoutB, HID_ * VD_ / 4);

  hipLaunchKernelGGL(k_gemm_bt<ushort_t>, dim3(CD_ / 128, M / 128), dim3(256), 0, stream,
                     xB, WqkvB, qkv_raw, M, CD_, HID_);
  hipLaunchKernelGGL(k_gemm_bt<ushort_t>, dim3(VD_ / 128, M / 128), dim3(256), 0, stream,
                     xB, WzB, zbuf, M, VD_, HID_);
  hipLaunchKernelGGL(k_proj_ba, dim3(M), dim3(256), 0, stream,
                     x, Wb, Wa, dtb, alog, betaB, gBuf);
  hipLaunchKernelGGL(k_conv_silu, dim3(M * CD_ / 4 / 256), dim3(256), 0, stream,
                     qkv_raw, cw, act);
  hipLaunchKernelGGL(k_l2norm_qk, dim3(M * 16 / 4), dim3(256), 0, stream, act);
  hipLaunchKernelGGL(k_prep, dim3(B_ * NV_ * 32), dim3(256), 0, stream,
                     act, gBuf, betaB, WkG, UlG, PmG, kTG, gtG);
  hipLaunchKernelGGL(k_scan, dim3(B_ * NV_), dim3(256), 0, stream,
                     act, WkG, UlG, PmG, kTG, gtG, obuf);
  hipLaunchKernelGGL(k_gate_rms, dim3(M * NV_ / 4), dim3(256), 0, stream,
                     obuf, zbuf, nw, outg);
  hipLaunchKernelGGL(k_gemm_bt<float>, dim3(HID_ / 128, M / 128), dim3(256), 0, stream,
                     outg, WoutB, (float*)d_out, M, HID_, VD_);
}